// Round 7
// baseline (245.700 us; speedup 1.0000x reference)
//
#include <hip/hip_runtime.h>

#define NN 100000
#define NE 1200000
#define DD 64
#define SCH 1024
#define SNB ((NN + SCH - 1) / SCH)              // 98 scan blocks

// ---- atomic-light CSR build: u8 LDS histogram + fused rank capture ----
#define KCH3 96                                 // edge chunks
#define CEH3 (NE / KCH3)                        // 12500 edges / chunk (exact)
#define P3 4                                    // dst partitions
#define BINS3 (NN / P3)                         // 25000 bins / partition
#define BINW3 (BINS3 / 4)                       // 6250 packed u32 words (25 KB LDS)
#define KSEG 4                                  // chunk-scan segments
#define KPS (KCH3 / KSEG)                       // 24 chunks per segment
#define NW4 (NN / 4)                            // 25000 packed u32 dst-words (NN = 4*NW4 exactly)
#define HISTB (KCH3 * P3)                       // 384 hist blocks
#define GEMMB ((NN + 255) / 256)                // 391 gemm blocks (256 rows each)

// bf16 helpers
static __device__ __forceinline__ unsigned short f2bf(float f) {
    unsigned int u = __float_as_uint(f);
    u += 0x7fffu + ((u >> 16) & 1u);
    return (unsigned short)(u >> 16);
}
static __device__ __forceinline__ float bf_lo(unsigned int u) { return __uint_as_float(u << 16); }
static __device__ __forceinline__ float bf_hi(unsigned int u) { return __uint_as_float(u & 0xffff0000u); }

// ---------------- merged: hist3 (blocks [0,HISTB)) || gemm1 (blocks [HISTB,..)) ----------------
__global__ __launch_bounds__(1024) void k_histgemm(const int* __restrict__ dst,
                                                   unsigned char* __restrict__ H,       // [KCH3][NN] u8
                                                   unsigned char* __restrict__ rank8,   // [NE] u8
                                                   const float* __restrict__ X,
                                                   const float* __restrict__ W,
                                                   unsigned short* __restrict__ Hb) {
    __shared__ union SM {
        unsigned int bins[BINW3];
        struct { float4 Ws4[64][16]; float Xs[64][68]; } g;
    } sm;
    int t = threadIdx.x;
    if (blockIdx.x < HISTB) {
        int k = blockIdx.x >> 2;          // P3 == 4
        int p = blockIdx.x & 3;
        for (int i = t; i < BINW3; i += 1024) sm.bins[i] = 0u;
        __syncthreads();
        int lo = p * BINS3;
        int beg = k * CEH3;
        for (int e4 = beg + t * 4; e4 < beg + CEH3; e4 += 4096) {
            int4 d4 = *(const int4*)&dst[e4];
            int dd[4] = {d4.x, d4.y, d4.z, d4.w};
#pragma unroll
            for (int j = 0; j < 4; ++j) {
                unsigned int r = (unsigned int)(dd[j] - lo);
                if (r < (unsigned int)BINS3) {
                    unsigned int sh = (r & 3u) << 3;
                    unsigned int old = atomicAdd(&sm.bins[r >> 2], 1u << sh);
                    rank8[e4 + j] = (unsigned char)((old >> sh) & 0xffu);
                }
            }
        }
        __syncthreads();
        unsigned int* Hw = (unsigned int*)(H + (size_t)k * NN + lo);
        for (int i = t; i < BINW3; i += 1024) Hw[i] = sm.bins[i];
    } else {
        const float4* W4 = (const float4*)W;
        sm.g.Ws4[t >> 4][t & 15] = W4[t];
        int row0 = (int)(blockIdx.x - HISTB) * 256;
        const float4* X4 = (const float4*)X;
        int r = t >> 4, q = t & 15;
#pragma unroll
        for (int s = 0; s < 4; ++s) {
            int row = row0 + s * 64 + r;
            float4 v = make_float4(0.f, 0.f, 0.f, 0.f);
            if (row < NN) v = X4[row * 16 + q];
            __syncthreads();
            *((float4*)&sm.g.Xs[r][q * 4]) = v;
            __syncthreads();
            float4 acc = make_float4(0.f, 0.f, 0.f, 0.f);
#pragma unroll 4
            for (int k = 0; k < 64; ++k) {
                float4 w = sm.g.Ws4[k][q];
                float x = sm.g.Xs[r][k];
                acc.x += x * w.x; acc.y += x * w.y; acc.z += x * w.z; acc.w += x * w.w;
            }
            if (row < NN) {
                ushort4 o;
                o.x = f2bf(acc.x); o.y = f2bf(acc.y); o.z = f2bf(acc.z); o.w = f2bf(acc.w);
                *((ushort4*)&Hb[(size_t)row * 64 + q * 4]) = o;
            }
        }
    }
}

// ---- segmented per-dst chunk prefix, pass A: per-segment sums ----
__global__ __launch_bounds__(256) void k_cseg_sum(const unsigned int* __restrict__ H32,
                                                  unsigned int* __restrict__ aux) {
    int wd = blockIdx.x * 256 + threadIdx.x;
    int seg = blockIdx.y;
    if (wd >= NW4) return;
    unsigned int s = 0;
#pragma unroll
    for (int k = 0; k < KPS; ++k)
        s += H32[(size_t)(seg * KPS + k) * NW4 + wd];
    aux[seg * NW4 + wd] = s;
}

// ---- pass B: prefix within segment; seg3 blocks ALSO fuse scan_local + degree-sort perm ----
// seg3 block b owns nodes [1024b, 1024b+1024): computes dinv, local rowptr, part,
// and a block-local counting sort by degree -> perm (gather load-balance: waves of
// 8 near-equal-degree nodes make dmax ~= deg, killing ~38% wasted iterations).
__global__ __launch_bounds__(256) void k_cseg_scan2(unsigned int* __restrict__ H32,
                                                    const unsigned int* __restrict__ aux,
                                                    int* __restrict__ rowptr,   // LOCAL excl prefix
                                                    int* __restrict__ part,
                                                    float* __restrict__ dinv,
                                                    int* __restrict__ perm) {
    __shared__ int wsum[4];
    __shared__ int hist[64];
    int t = threadIdx.x;
    int wd = blockIdx.x * 256 + t;
    int seg = blockIdx.y;
    bool valid = wd < NW4;
    unsigned int s = 0;
    if (valid) {
        unsigned int base = 0;
        for (int i = 0; i < seg; ++i) base += aux[i * NW4 + wd];
        s = base;
#pragma unroll
        for (int k = 0; k < KPS; ++k) {
            size_t idx = (size_t)(seg * KPS + k) * NW4 + wd;
            unsigned int v = H32[idx];
            H32[idx] = s;
            s += v;                      // byte-wise SWAR: no carry since deg < 256
        }
    }
    if (seg != KSEG - 1) return;         // uniform per block
    int d0 = valid ? (int)(s & 0xffu) : 0;
    int d1 = valid ? (int)((s >> 8) & 0xffu) : 0;
    int d2 = valid ? (int)((s >> 16) & 0xffu) : 0;
    int d3 = valid ? (int)(s >> 24) : 0;
    int idx = blockIdx.x * SCH + t * 4;  // == 4*wd
    if (valid) {
        float4 dv;
        dv.x = rsqrtf((float)d0 + 1.0f);
        dv.y = rsqrtf((float)d1 + 1.0f);
        dv.z = rsqrtf((float)d2 + 1.0f);
        dv.w = rsqrtf((float)d3 + 1.0f);
        *(float4*)&dinv[idx] = dv;
    }
    int ssum = d0 + d1 + d2 + d3;
    int lane = t & 63;
    int incl = ssum;
#pragma unroll
    for (int off = 1; off < 64; off <<= 1) {
        int v = __shfl_up(incl, off);
        if (lane >= off) incl += v;
    }
    int wv = t >> 6;
    if (lane == 63) wsum[wv] = incl;
    if (t < 64) hist[t] = 0;
    __syncthreads();
    int woff = 0;
#pragma unroll
    for (int i = 0; i < 4; ++i) if (i < wv) woff += wsum[i];
    int excl = woff + incl - ssum;
    int r0 = 0, r1 = 0, r2 = 0, r3 = 0;
    if (valid) {
        int4 rp = make_int4(excl, excl + d0, excl + d0 + d1, excl + d0 + d1 + d2);
        *(int4*)&rowptr[idx] = rp;
        // degree-sort rank capture (bin clamp only affects ordering, not bijectivity)
        r0 = atomicAdd(&hist[min(d0, 63)], 1);
        r1 = atomicAdd(&hist[min(d1, 63)], 1);
        r2 = atomicAdd(&hist[min(d2, 63)], 1);
        r3 = atomicAdd(&hist[min(d3, 63)], 1);
    }
    if (t == 255) part[blockIdx.x] = woff + incl;
    __syncthreads();
    if (t < 64) {                        // wave 0: exclusive prefix of the 64 bins
        int v = hist[t];
        int inc = v;
#pragma unroll
        for (int off = 1; off < 64; off <<= 1) {
            int u = __shfl_up(inc, off);
            if (t >= off) inc += u;
        }
        hist[t] = inc - v;
    }
    __syncthreads();
    if (valid) {
        int base = blockIdx.x * SCH;
        perm[base + hist[min(d0, 63)] + r0] = idx;
        perm[base + hist[min(d1, 63)] + r1] = idx + 1;
        perm[base + hist[min(d2, 63)] + r2] = idx + 2;
        perm[base + hist[min(d3, 63)] + r3] = idx + 3;
    }
}

// ---- scan over the 98 block totals; also park last block's local total at rowptr[NN] ----
__global__ __launch_bounds__(128) void k_scan_part(int* __restrict__ part, int* __restrict__ rowptr) {
    __shared__ int sm[128];
    int t = threadIdx.x;
    int v = (t < SNB) ? part[t] : 0;
    sm[t] = v;
    __syncthreads();
    for (int off = 1; off < 128; off <<= 1) {
        int add = (t >= off) ? sm[t - off] : 0;
        __syncthreads();
        sm[t] += add;
        __syncthreads();
    }
    if (t == SNB - 1) rowptr[NN] = v;
    if (t < SNB) part[t] = sm[t] - v;
}

// ---- fill + coef fused: cc[pos] = {src, dinv[src]*dinv[dst]} ----
__global__ __launch_bounds__(256) void k_fill4(const int* __restrict__ src,
                                               const int* __restrict__ dst,
                                               const unsigned char* __restrict__ rank8,
                                               const unsigned char* __restrict__ H,
                                               const int* __restrict__ rowptr,
                                               const int* __restrict__ part,
                                               const float* __restrict__ dinv,
                                               int2* __restrict__ cc) {
    int e4 = (blockIdx.x * 256 + threadIdx.x) * 4;
    if (e4 >= NE) return;
    int4 d4 = *(const int4*)&dst[e4];
    int4 s4 = *(const int4*)&src[e4];
    unsigned int r4 = *(const unsigned int*)&rank8[e4];
    int dd[4] = {d4.x, d4.y, d4.z, d4.w};
    int ss[4] = {s4.x, s4.y, s4.z, s4.w};
    int k = e4 / CEH3;                   // CEH3 % 4 == 0 -> whole int4 in one chunk
#pragma unroll
    for (int j = 0; j < 4; ++j) {
        int d = dd[j], s = ss[j];
        int base = rowptr[d] + part[d >> 10] + (int)H[(size_t)k * NN + d];
        int pos = base + (int)((r4 >> (8 * j)) & 0xffu);
        cc[pos] = make_int2(s, __float_as_int(dinv[s] * dinv[d]));
    }
}

// ---------------- legacy fallback kernels ----------------
__global__ void k_hist_rank(const int* __restrict__ dst, int* __restrict__ degi,
                            int* __restrict__ rank, int ne) {
    int i = blockIdx.x * blockDim.x + threadIdx.x;
    if (i < ne) rank[i] = atomicAdd(&degi[dst[i]], 1);
}

__global__ __launch_bounds__(256) void k_scan_local(const int* __restrict__ degi,
                                                    int* __restrict__ rowptr,
                                                    int* __restrict__ part,
                                                    float* __restrict__ dinv) {
    __shared__ int wsum[4];
    int t = threadIdx.x;
    int idx = blockIdx.x * SCH + t * 4;
    int d0 = 0, d1 = 0, d2 = 0, d3 = 0;
    if (idx + 3 < NN) {
        int4 v = *(const int4*)&degi[idx];
        d0 = v.x; d1 = v.y; d2 = v.z; d3 = v.w;
        float4 dv;
        dv.x = rsqrtf((float)d0 + 1.0f);
        dv.y = rsqrtf((float)d1 + 1.0f);
        dv.z = rsqrtf((float)d2 + 1.0f);
        dv.w = rsqrtf((float)d3 + 1.0f);
        *(float4*)&dinv[idx] = dv;
    } else {
        if (idx     < NN) { d0 = degi[idx];     dinv[idx]     = rsqrtf((float)d0 + 1.0f); }
        if (idx + 1 < NN) { d1 = degi[idx + 1]; dinv[idx + 1] = rsqrtf((float)d1 + 1.0f); }
        if (idx + 2 < NN) { d2 = degi[idx + 2]; dinv[idx + 2] = rsqrtf((float)d2 + 1.0f); }
        if (idx + 3 < NN) { d3 = degi[idx + 3]; dinv[idx + 3] = rsqrtf((float)d3 + 1.0f); }
    }
    int s = d0 + d1 + d2 + d3;
    int lane = t & 63;
    int incl = s;
#pragma unroll
    for (int off = 1; off < 64; off <<= 1) {
        int v = __shfl_up(incl, off);
        if (lane >= off) incl += v;
    }
    int wv = t >> 6;
    if (lane == 63) wsum[wv] = incl;
    __syncthreads();
    int woff = 0;
#pragma unroll
    for (int i = 0; i < 4; ++i) if (i < wv) woff += wsum[i];
    int excl = woff + incl - s;
    if (idx     < NN) rowptr[idx]     = excl;
    if (idx + 1 < NN) rowptr[idx + 1] = excl + d0;
    if (idx + 2 < NN) rowptr[idx + 2] = excl + d0 + d1;
    if (idx + 3 < NN) rowptr[idx + 3] = excl + d0 + d1 + d2;
    if (t == 255) part[blockIdx.x] = woff + incl;
}

__global__ void k_scan_add(int* __restrict__ rowptr, const int* __restrict__ part) {
    int i = blockIdx.x * blockDim.x + threadIdx.x;
    if (i < NN) rowptr[i] += part[i >> 10];
    if (i == 0) rowptr[NN] = NE;
}

__global__ void k_fill_rank(const int* __restrict__ src, const int* __restrict__ dst,
                            const int* __restrict__ rank, const int* __restrict__ rowptr,
                            int* __restrict__ csr_src, int ne) {
    int e = blockIdx.x * blockDim.x + threadIdx.x;
    if (e < ne) csr_src[rowptr[dst[e]] + rank[e]] = src[e];
}

__global__ __launch_bounds__(256) void k_pack(const int* __restrict__ rowptr,
                                              const int* __restrict__ csr,
                                              const float* __restrict__ dinv,
                                              int2* __restrict__ cc) {
    int n = blockIdx.x * 256 + threadIdx.x;
    if (n >= NN) return;
    float dn = dinv[n];
    for (int e = rowptr[n]; e < rowptr[n + 1]; ++e) {
        int s = csr[e];
        cc[e] = make_int2(s, __float_as_int(dinv[s] * dn));
    }
}

__global__ void k_iota(int* __restrict__ perm) {
    int i = blockIdx.x * blockDim.x + threadIdx.x;
    if (i < NN) perm[i] = i;
}

__global__ __launch_bounds__(256) void k_gemm_bf(const float* __restrict__ X,
                                                 const float* __restrict__ W,
                                                 unsigned short* __restrict__ Hb,
                                                 int nrows) {
    __shared__ float4 Ws4[64][16];
    __shared__ float  Xs[64][68];
    int tid = threadIdx.x;
    const float4* W4 = (const float4*)W;
    for (int i = tid; i < 64 * 16; i += 256) Ws4[i >> 4][i & 15] = W4[i];
    int row0 = blockIdx.x * 64;
    const float4* X4 = (const float4*)X;
    for (int i = tid; i < 64 * 16; i += 256) {
        int r = i >> 4, q = i & 15;
        int row = row0 + r;
        float4 v = make_float4(0.f, 0.f, 0.f, 0.f);
        if (row < nrows) v = X4[row * 16 + q];
        *((float4*)&Xs[r][q * 4]) = v;
    }
    __syncthreads();
    int c4 = tid & 15;
    int rg = tid >> 4;
    float4 acc0 = make_float4(0.f, 0.f, 0.f, 0.f);
    float4 acc1 = acc0, acc2 = acc0, acc3 = acc0;
#pragma unroll 4
    for (int k = 0; k < 64; ++k) {
        float4 w = Ws4[k][c4];
        float x0 = Xs[rg * 4 + 0][k];
        float x1 = Xs[rg * 4 + 1][k];
        float x2 = Xs[rg * 4 + 2][k];
        float x3 = Xs[rg * 4 + 3][k];
        acc0.x += x0 * w.x; acc0.y += x0 * w.y; acc0.z += x0 * w.z; acc0.w += x0 * w.w;
        acc1.x += x1 * w.x; acc1.y += x1 * w.y; acc1.z += x1 * w.z; acc1.w += x1 * w.w;
        acc2.x += x2 * w.x; acc2.y += x2 * w.y; acc2.z += x2 * w.z; acc2.w += x2 * w.w;
        acc3.x += x3 * w.x; acc3.y += x3 * w.y; acc3.z += x3 * w.z; acc3.w += x3 * w.w;
    }
    float4 accs[4] = {acc0, acc1, acc2, acc3};
#pragma unroll
    for (int i = 0; i < 4; ++i) {
        int row = row0 + rg * 4 + i;
        if (row < nrows) {
            ushort4 o;
            o.x = f2bf(accs[i].x); o.y = f2bf(accs[i].y);
            o.z = f2bf(accs[i].z); o.w = f2bf(accs[i].w);
            *((ushort4*)&Hb[row * 64 + c4 * 4]) = o;
        }
    }
}

// ---------------- shared gather core: 8 nodes/wave, 4-deep pipeline, int2 stream ----------------
static __device__ __forceinline__ void gather8(const unsigned short* __restrict__ Hb,
                                               const int2* __restrict__ cc,
                                               int e0, int deg, int dmax, int cg,
                                               float acc[8]) {
#define LDE(T, S, C) { bool _v = (T) < deg; int2 _w = _v ? cc[e0 + (T)] : make_int2(0, 0); \
                       S = _w.x; C = __int_as_float(_w.y); }
#define GAT(U, S) U = *(const uint4*)(Hb + (size_t)(S) * 64 + cg * 8);
#define CONS(U, C) { acc[0] += bf_lo(U.x) * (C);  acc[1] += bf_hi(U.x) * (C); \
                     acc[2] += bf_lo(U.y) * (C);  acc[3] += bf_hi(U.y) * (C); \
                     acc[4] += bf_lo(U.z) * (C);  acc[5] += bf_hi(U.z) * (C); \
                     acc[6] += bf_lo(U.w) * (C);  acc[7] += bf_hi(U.w) * (C); }
    int s0, s1, s2, s3; float c0, c1, c2, c3;
    LDE(0, s0, c0); LDE(1, s1, c1); LDE(2, s2, c2); LDE(3, s3, c3);
    uint4 u0, u1, u2, u3;
    GAT(u0, s0); GAT(u1, s1); GAT(u2, s2); GAT(u3, s3);
    for (int t = 0; t < dmax; t += 4) {
        int sn0, sn1, sn2, sn3; float cn0, cn1, cn2, cn3;
        LDE(t + 4, sn0, cn0); LDE(t + 5, sn1, cn1);
        LDE(t + 6, sn2, cn2); LDE(t + 7, sn3, cn3);
        CONS(u0, c0); GAT(u0, sn0); c0 = cn0;
        CONS(u1, c1); GAT(u1, sn1); c1 = cn1;
        CONS(u2, c2); GAT(u2, sn2); c2 = cn2;
        CONS(u3, c3); GAT(u3, sn3); c3 = cn3;
    }
#undef LDE
#undef GAT
#undef CONS
}

// ---------------- reduce layer1 + gemm2 fused: h1 never touches HBM ----------------
__global__ __launch_bounds__(256) void k_reduce_g2(const unsigned short* __restrict__ Hb,
                                                   const int* __restrict__ rowptr,
                                                   const int* __restrict__ part,
                                                   const int2* __restrict__ cc,
                                                   const float* __restrict__ dinv,
                                                   const int* __restrict__ perm,
                                                   const float* __restrict__ bias,
                                                   const float* __restrict__ W2,
                                                   unsigned short* __restrict__ Hb2) {
    __shared__ float4 Ws4[64][16];
    __shared__ float rows[32][68];
    int t = threadIdx.x;
    const float4* W4 = (const float4*)W2;
    for (int i = t; i < 1024; i += 256) Ws4[i >> 4][i & 15] = W4[i];   // hides under gather loop

    int n = perm[blockIdx.x * 32 + (t >> 3)];   // degree-sorted assignment
    int cg = t & 7;
    float din = dinv[n];
    uint4 us = *(const uint4*)(Hb + (size_t)n * 64 + cg * 8);
    int rp0 = rowptr[n] + part[n >> 10];
    int rp1 = rowptr[n + 1] + part[(n + 1) >> 10];
    int e0 = rp0, deg = rp1 - rp0;
    int dmax = deg;
    dmax = max(dmax, __shfl_xor(dmax, 8));
    dmax = max(dmax, __shfl_xor(dmax, 16));
    dmax = max(dmax, __shfl_xor(dmax, 32));

    float acc[8];
#pragma unroll
    for (int j = 0; j < 8; ++j) acc[j] = 0.f;
    gather8(Hb, cc, e0, deg, dmax, cg, acc);

    // h1 = relu(agg + self + b1) -> LDS rows
    float ddn = din * din;
    float4 b0 = *(const float4*)(bias + cg * 8);
    float4 b1 = *(const float4*)(bias + cg * 8 + 4);
    float4 o0, o1;
    o0.x = fmaxf(acc[0] + bf_lo(us.x) * ddn + b0.x, 0.f);
    o0.y = fmaxf(acc[1] + bf_hi(us.x) * ddn + b0.y, 0.f);
    o0.z = fmaxf(acc[2] + bf_lo(us.y) * ddn + b0.z, 0.f);
    o0.w = fmaxf(acc[3] + bf_hi(us.y) * ddn + b0.w, 0.f);
    o1.x = fmaxf(acc[4] + bf_lo(us.z) * ddn + b1.x, 0.f);
    o1.y = fmaxf(acc[5] + bf_hi(us.z) * ddn + b1.y, 0.f);
    o1.z = fmaxf(acc[6] + bf_lo(us.w) * ddn + b1.z, 0.f);
    o1.w = fmaxf(acc[7] + bf_hi(us.w) * ddn + b1.w, 0.f);
    int node = t >> 3;
    *(float4*)&rows[node][cg * 8]     = o0;
    *(float4*)&rows[node][cg * 8 + 4] = o1;
    __syncthreads();

    // gemm2: thread (node, c2) computes cols c2*8..c2*8+7 of Hb2[n]
    int c2 = t & 7;
    float a0 = 0.f, a1 = 0.f, a2 = 0.f, a3 = 0.f, a4 = 0.f, a5 = 0.f, a6 = 0.f, a7 = 0.f;
#pragma unroll 4
    for (int k = 0; k < 64; ++k) {
        float r = rows[node][k];
        float4 w0 = Ws4[k][c2 * 2];
        float4 w1 = Ws4[k][c2 * 2 + 1];
        a0 += r * w0.x; a1 += r * w0.y; a2 += r * w0.z; a3 += r * w0.w;
        a4 += r * w1.x; a5 += r * w1.y; a6 += r * w1.z; a7 += r * w1.w;
    }
    uint4 pk;
    pk.x = (unsigned int)f2bf(a0) | ((unsigned int)f2bf(a1) << 16);
    pk.y = (unsigned int)f2bf(a2) | ((unsigned int)f2bf(a3) << 16);
    pk.z = (unsigned int)f2bf(a4) | ((unsigned int)f2bf(a5) << 16);
    pk.w = (unsigned int)f2bf(a6) | ((unsigned int)f2bf(a7) << 16);
    *(uint4*)&Hb2[(size_t)n * 64 + c2 * 8] = pk;
}

// ---------------- final reduce (layer 2): writes h to both output halves ----------------
__global__ __launch_bounds__(256) void k_reduce2(const unsigned short* __restrict__ Hb,
                                                 const int* __restrict__ rowptr,
                                                 const int* __restrict__ part,
                                                 const int2* __restrict__ cc,
                                                 const float* __restrict__ dinv,
                                                 const int* __restrict__ perm,
                                                 const float* __restrict__ bias,
                                                 float* __restrict__ out0,
                                                 float* __restrict__ out1) {
    int n = perm[blockIdx.x * 32 + (threadIdx.x >> 3)];
    int cg = threadIdx.x & 7;
    float din = dinv[n];
    uint4 us = *(const uint4*)(Hb + (size_t)n * 64 + cg * 8);
    int rp0 = rowptr[n] + part[n >> 10];
    int rp1 = rowptr[n + 1] + part[(n + 1) >> 10];
    int e0 = rp0, deg = rp1 - rp0;
    int dmax = deg;
    dmax = max(dmax, __shfl_xor(dmax, 8));
    dmax = max(dmax, __shfl_xor(dmax, 16));
    dmax = max(dmax, __shfl_xor(dmax, 32));

    float acc[8];
#pragma unroll
    for (int j = 0; j < 8; ++j) acc[j] = 0.f;
    gather8(Hb, cc, e0, deg, dmax, cg, acc);

    float ddn = din * din;
    float4 b0 = *(const float4*)(bias + cg * 8);
    float4 b1 = *(const float4*)(bias + cg * 8 + 4);
    float4 o0, o1;
    o0.x = acc[0] + bf_lo(us.x) * ddn + b0.x;
    o0.y = acc[1] + bf_hi(us.x) * ddn + b0.y;
    o0.z = acc[2] + bf_lo(us.y) * ddn + b0.z;
    o0.w = acc[3] + bf_hi(us.y) * ddn + b0.w;
    o1.x = acc[4] + bf_lo(us.z) * ddn + b1.x;
    o1.y = acc[5] + bf_hi(us.z) * ddn + b1.y;
    o1.z = acc[6] + bf_lo(us.w) * ddn + b1.z;
    o1.w = acc[7] + bf_hi(us.w) * ddn + b1.w;
    *(float4*)(out0 + (size_t)n * 64 + cg * 8)     = o0;
    *(float4*)(out0 + (size_t)n * 64 + cg * 8 + 4) = o1;
    *(float4*)(out1 + (size_t)n * 64 + cg * 8)     = o0;
    *(float4*)(out1 + (size_t)n * 64 + cg * 8 + 4) = o1;
}

extern "C" void kernel_launch(void* const* d_in, const int* in_sizes, int n_in,
                              void* d_out, int out_size, void* d_ws, size_t ws_size,
                              hipStream_t stream) {
    const float* x  = (const float*)d_in[0];
    const int*   ei = (const int*)d_in[1];     // [2, NE]: src row then dst row
    const float* W1 = (const float*)d_in[2];
    const float* b1 = (const float*)d_in[3];
    const float* W2 = (const float*)d_in[4];
    const float* b2 = (const float*)d_in[5];
    const int* src = ei;
    const int* dst = ei + NE;

    float* A = (float*)d_out;                   // half 0: final h
    float* B = (float*)d_out + (size_t)NN * DD; // half 1: final h

    char* w = (char*)d_ws;
    size_t off = 0;
    auto alloc = [&](size_t bytes) { void* p = w + off; off += (bytes + 255) & ~(size_t)255; return p; };
    float* dinv   = (float*)alloc(NN * sizeof(float));
    int*   degi   = (int*)  alloc(NN * sizeof(int));            // legacy only
    int*   cnt    = (int*)  alloc(NN * sizeof(int));            // new: cseg aux (exactly KSEG*NW4 ints)
    int*   rowptr = (int*)  alloc((NN + 1) * sizeof(int));
    int*   part   = (int*)  alloc(512 * sizeof(int));
    int*   perm   = (int*)  alloc(NN * sizeof(int));            // degree-sorted node order
    int*   csr    = (int*)  alloc(NE * sizeof(int));            // legacy only
    int2*  cc     = (int2*) alloc(NE * sizeof(int2));           // {src, coef} packed, 9.6 MB
    void*  uni    = alloc((size_t)NN * DD * sizeof(unsigned short));
    unsigned char* Hh    = (unsigned char*)uni;
    unsigned char* rank8 = (unsigned char*)uni + (size_t)KCH3 * NN;
    unsigned short* Bb2  = (unsigned short*)uni;
    unsigned short* Bb1 = (unsigned short*)alloc((size_t)NN * DD * sizeof(unsigned short));
    int* rank = (int*)Bb1;                      // legacy rank aliases Bb1
    size_t off_total = off;

    bool new_path = (ws_size >= off_total);

    if (new_path) {
        // 1. hist (+rank capture) || gemm1 — independent, merged
        k_histgemm<<<HISTB + GEMMB, 1024, 0, stream>>>(dst, Hh, rank8, x, W1, Bb1);
        // 2-3. per-dst chunk prefix; seg3 fuses dinv + local rowptr + part + degree-sort perm
        dim3 cgrid((NW4 + 255) / 256, KSEG);
        k_cseg_sum<<<cgrid, 256, 0, stream>>>((unsigned int*)Hh, (unsigned int*)cnt);
        k_cseg_scan2<<<cgrid, 256, 0, stream>>>((unsigned int*)Hh, (const unsigned int*)cnt,
                                                rowptr, part, dinv, perm);
        // 4. part scan (+rowptr[NN] park)
        k_scan_part<<<1, 128, 0, stream>>>(part, rowptr);
        // 5. fill + coef fused
        k_fill4<<<(NE / 4 + 255) / 256, 256, 0, stream>>>(src, dst, rank8, Hh, rowptr, part, dinv, cc);
        // 6. reduce layer1 + gemm2 fused -> Bb2 (H region now dead)
        k_reduce_g2<<<NN / 32, 256, 0, stream>>>(Bb1, rowptr, part, cc, dinv, perm, b1, W2, Bb2);
        // 7. final reduce -> both output halves
        k_reduce2<<<NN / 32, 256, 0, stream>>>(Bb2, rowptr, part, cc, dinv, perm, b2, A, B);
    } else {
        // legacy rank path
        hipMemsetAsync(degi, 0, NN * sizeof(int), stream);
        k_hist_rank<<<(NE + 255) / 256, 256, 0, stream>>>(dst, degi, rank, NE);
        k_scan_local<<<SNB, 256, 0, stream>>>(degi, rowptr, part, dinv);
        k_scan_part<<<1, 128, 0, stream>>>(part, rowptr);
        k_scan_add<<<(NN + 255) / 256, 256, 0, stream>>>(rowptr, part);
        hipMemsetAsync(part, 0, 512 * sizeof(int), stream);
        k_fill_rank<<<(NE + 255) / 256, 256, 0, stream>>>(src, dst, rank, rowptr, csr, NE);
        k_pack<<<(NN + 255) / 256, 256, 0, stream>>>(rowptr, csr, dinv, cc);
        k_iota<<<(NN + 255) / 256, 256, 0, stream>>>(perm);
        k_gemm_bf<<<(NN + 63) / 64, 256, 0, stream>>>(x, W1, Bb1, NN);
        k_reduce_g2<<<NN / 32, 256, 0, stream>>>(Bb1, rowptr, part, cc, dinv, perm, b1, W2, Bb2);
        k_reduce2<<<NN / 32, 256, 0, stream>>>(Bb2, rowptr, part, cc, dinv, perm, b2, A, B);
    }
}

// Round 8
// 241.681 us; speedup vs baseline: 1.0166x; 1.0166x over previous
//
#include <hip/hip_runtime.h>

#define NN 100000
#define NE 1200000
#define DD 64
#define SCH 1024
#define SNB ((NN + SCH - 1) / SCH)              // 98 scan blocks

// ---- atomic-light CSR build: u8 LDS histogram + fused rank capture ----
#define KCH3 96                                 // edge chunks
#define CEH3 (NE / KCH3)                        // 12500 edges / chunk (exact)
#define P3 4                                    // dst partitions
#define BINS3 (NN / P3)                         // 25000 bins / partition
#define BINW3 (BINS3 / 4)                       // 6250 packed u32 words (25 KB LDS)
#define KSEG 4                                  // chunk-scan segments
#define KPS (KCH3 / KSEG)                       // 24 chunks per segment
#define NW4 (NN / 4)                            // 25000 packed u32 dst-words (NN = 4*NW4 exactly)
#define HISTB (KCH3 * P3)                       // 384 hist blocks
#define GEMMB ((NN + 255) / 256)                // 391 gemm blocks (256 rows each)

// bf16 helpers
static __device__ __forceinline__ unsigned short f2bf(float f) {
    unsigned int u = __float_as_uint(f);
    u += 0x7fffu + ((u >> 16) & 1u);
    return (unsigned short)(u >> 16);
}
static __device__ __forceinline__ float bf_lo(unsigned int u) { return __uint_as_float(u << 16); }
static __device__ __forceinline__ float bf_hi(unsigned int u) { return __uint_as_float(u & 0xffff0000u); }

// ---------------- merged: hist3 (blocks [0,HISTB)) || gemm1 (blocks [HISTB,..)) ----------------
__global__ __launch_bounds__(1024) void k_histgemm(const int* __restrict__ dst,
                                                   unsigned char* __restrict__ H,       // [KCH3][NN] u8
                                                   unsigned char* __restrict__ rank8,   // [NE] u8
                                                   const float* __restrict__ X,
                                                   const float* __restrict__ W,
                                                   unsigned short* __restrict__ Hb) {
    __shared__ union SM {
        unsigned int bins[BINW3];
        struct { float4 Ws4[64][16]; float Xs[64][68]; } g;
    } sm;
    int t = threadIdx.x;
    if (blockIdx.x < HISTB) {
        int k = blockIdx.x >> 2;          // P3 == 4
        int p = blockIdx.x & 3;
        for (int i = t; i < BINW3; i += 1024) sm.bins[i] = 0u;
        __syncthreads();
        int lo = p * BINS3;
        int beg = k * CEH3;
        for (int e4 = beg + t * 4; e4 < beg + CEH3; e4 += 4096) {
            int4 d4 = *(const int4*)&dst[e4];
            int dd[4] = {d4.x, d4.y, d4.z, d4.w};
#pragma unroll
            for (int j = 0; j < 4; ++j) {
                unsigned int r = (unsigned int)(dd[j] - lo);
                if (r < (unsigned int)BINS3) {
                    unsigned int sh = (r & 3u) << 3;
                    unsigned int old = atomicAdd(&sm.bins[r >> 2], 1u << sh);
                    rank8[e4 + j] = (unsigned char)((old >> sh) & 0xffu);
                }
            }
        }
        __syncthreads();
        unsigned int* Hw = (unsigned int*)(H + (size_t)k * NN + lo);
        for (int i = t; i < BINW3; i += 1024) Hw[i] = sm.bins[i];
    } else {
        const float4* W4 = (const float4*)W;
        sm.g.Ws4[t >> 4][t & 15] = W4[t];
        int row0 = (int)(blockIdx.x - HISTB) * 256;
        const float4* X4 = (const float4*)X;
        int r = t >> 4, q = t & 15;
#pragma unroll
        for (int s = 0; s < 4; ++s) {
            int row = row0 + s * 64 + r;
            float4 v = make_float4(0.f, 0.f, 0.f, 0.f);
            if (row < NN) v = X4[row * 16 + q];
            __syncthreads();
            *((float4*)&sm.g.Xs[r][q * 4]) = v;
            __syncthreads();
            float4 acc = make_float4(0.f, 0.f, 0.f, 0.f);
#pragma unroll 4
            for (int k = 0; k < 64; ++k) {
                float4 w = sm.g.Ws4[k][q];
                float x = sm.g.Xs[r][k];
                acc.x += x * w.x; acc.y += x * w.y; acc.z += x * w.z; acc.w += x * w.w;
            }
            if (row < NN) {
                ushort4 o;
                o.x = f2bf(acc.x); o.y = f2bf(acc.y); o.z = f2bf(acc.z); o.w = f2bf(acc.w);
                *((ushort4*)&Hb[(size_t)row * 64 + q * 4]) = o;
            }
        }
    }
}

// ---- segmented per-dst chunk prefix, pass A: per-segment sums ----
__global__ __launch_bounds__(256) void k_cseg_sum(const unsigned int* __restrict__ H32,
                                                  unsigned int* __restrict__ aux) {
    int wd = blockIdx.x * 256 + threadIdx.x;
    int seg = blockIdx.y;
    if (wd >= NW4) return;
    unsigned int s = 0;
#pragma unroll
    for (int k = 0; k < KPS; ++k)
        s += H32[(size_t)(seg * KPS + k) * NW4 + wd];
    aux[seg * NW4 + wd] = s;
}

// ---- pass B: prefix within segment; seg3 blocks ALSO fuse scan_local (dinv/rowptr/part) ----
__global__ __launch_bounds__(256) void k_cseg_scan2(unsigned int* __restrict__ H32,
                                                    const unsigned int* __restrict__ aux,
                                                    int* __restrict__ rowptr,   // LOCAL excl prefix
                                                    int* __restrict__ part,
                                                    float* __restrict__ dinv) {
    __shared__ int wsum[4];
    int t = threadIdx.x;
    int wd = blockIdx.x * 256 + t;
    int seg = blockIdx.y;
    bool valid = wd < NW4;
    unsigned int s = 0;
    if (valid) {
        unsigned int base = 0;
        for (int i = 0; i < seg; ++i) base += aux[i * NW4 + wd];
        s = base;
#pragma unroll
        for (int k = 0; k < KPS; ++k) {
            size_t idx = (size_t)(seg * KPS + k) * NW4 + wd;
            unsigned int v = H32[idx];
            H32[idx] = s;
            s += v;                      // byte-wise SWAR: no carry since deg < 256
        }
    }
    if (seg != KSEG - 1) return;         // uniform per block
    int d0 = valid ? (int)(s & 0xffu) : 0;
    int d1 = valid ? (int)((s >> 8) & 0xffu) : 0;
    int d2 = valid ? (int)((s >> 16) & 0xffu) : 0;
    int d3 = valid ? (int)(s >> 24) : 0;
    int idx = blockIdx.x * SCH + t * 4;  // == 4*wd
    if (valid) {
        float4 dv;
        dv.x = rsqrtf((float)d0 + 1.0f);
        dv.y = rsqrtf((float)d1 + 1.0f);
        dv.z = rsqrtf((float)d2 + 1.0f);
        dv.w = rsqrtf((float)d3 + 1.0f);
        *(float4*)&dinv[idx] = dv;
    }
    int ssum = d0 + d1 + d2 + d3;
    int lane = t & 63;
    int incl = ssum;
#pragma unroll
    for (int off = 1; off < 64; off <<= 1) {
        int v = __shfl_up(incl, off);
        if (lane >= off) incl += v;
    }
    int wv = t >> 6;
    if (lane == 63) wsum[wv] = incl;
    __syncthreads();
    int woff = 0;
#pragma unroll
    for (int i = 0; i < 4; ++i) if (i < wv) woff += wsum[i];
    int excl = woff + incl - ssum;
    if (valid) {
        int4 rp = make_int4(excl, excl + d0, excl + d0 + d1, excl + d0 + d1 + d2);
        *(int4*)&rowptr[idx] = rp;
    }
    if (t == 255) part[blockIdx.x] = woff + incl;
}

// ---- scan over the 98 block totals; also park last block's local total at rowptr[NN] ----
__global__ __launch_bounds__(128) void k_scan_part(int* __restrict__ part, int* __restrict__ rowptr) {
    __shared__ int sm[128];
    int t = threadIdx.x;
    int v = (t < SNB) ? part[t] : 0;
    sm[t] = v;
    __syncthreads();
    for (int off = 1; off < 128; off <<= 1) {
        int add = (t >= off) ? sm[t - off] : 0;
        __syncthreads();
        sm[t] += add;
        __syncthreads();
    }
    if (t == SNB - 1) rowptr[NN] = v;
    if (t < SNB) part[t] = sm[t] - v;
}

// ---- fill + coef fused: cc[pos] = {src, dinv[src]*dinv[dst]} ----
__global__ __launch_bounds__(256) void k_fill4(const int* __restrict__ src,
                                               const int* __restrict__ dst,
                                               const unsigned char* __restrict__ rank8,
                                               const unsigned char* __restrict__ H,
                                               const int* __restrict__ rowptr,
                                               const int* __restrict__ part,
                                               const float* __restrict__ dinv,
                                               int2* __restrict__ cc) {
    int e4 = (blockIdx.x * 256 + threadIdx.x) * 4;
    if (e4 >= NE) return;
    int4 d4 = *(const int4*)&dst[e4];
    int4 s4 = *(const int4*)&src[e4];
    unsigned int r4 = *(const unsigned int*)&rank8[e4];
    int dd[4] = {d4.x, d4.y, d4.z, d4.w};
    int ss[4] = {s4.x, s4.y, s4.z, s4.w};
    int k = e4 / CEH3;                   // CEH3 % 4 == 0 -> whole int4 in one chunk
#pragma unroll
    for (int j = 0; j < 4; ++j) {
        int d = dd[j], s = ss[j];
        int base = rowptr[d] + part[d >> 10] + (int)H[(size_t)k * NN + d];
        int pos = base + (int)((r4 >> (8 * j)) & 0xffu);
        cc[pos] = make_int2(s, __float_as_int(dinv[s] * dinv[d]));
    }
}

// ---------------- legacy fallback kernels ----------------
__global__ void k_hist_rank(const int* __restrict__ dst, int* __restrict__ degi,
                            int* __restrict__ rank, int ne) {
    int i = blockIdx.x * blockDim.x + threadIdx.x;
    if (i < ne) rank[i] = atomicAdd(&degi[dst[i]], 1);
}

__global__ __launch_bounds__(256) void k_scan_local(const int* __restrict__ degi,
                                                    int* __restrict__ rowptr,
                                                    int* __restrict__ part,
                                                    float* __restrict__ dinv) {
    __shared__ int wsum[4];
    int t = threadIdx.x;
    int idx = blockIdx.x * SCH + t * 4;
    int d0 = 0, d1 = 0, d2 = 0, d3 = 0;
    if (idx + 3 < NN) {
        int4 v = *(const int4*)&degi[idx];
        d0 = v.x; d1 = v.y; d2 = v.z; d3 = v.w;
        float4 dv;
        dv.x = rsqrtf((float)d0 + 1.0f);
        dv.y = rsqrtf((float)d1 + 1.0f);
        dv.z = rsqrtf((float)d2 + 1.0f);
        dv.w = rsqrtf((float)d3 + 1.0f);
        *(float4*)&dinv[idx] = dv;
    } else {
        if (idx     < NN) { d0 = degi[idx];     dinv[idx]     = rsqrtf((float)d0 + 1.0f); }
        if (idx + 1 < NN) { d1 = degi[idx + 1]; dinv[idx + 1] = rsqrtf((float)d1 + 1.0f); }
        if (idx + 2 < NN) { d2 = degi[idx + 2]; dinv[idx + 2] = rsqrtf((float)d2 + 1.0f); }
        if (idx + 3 < NN) { d3 = degi[idx + 3]; dinv[idx + 3] = rsqrtf((float)d3 + 1.0f); }
    }
    int s = d0 + d1 + d2 + d3;
    int lane = t & 63;
    int incl = s;
#pragma unroll
    for (int off = 1; off < 64; off <<= 1) {
        int v = __shfl_up(incl, off);
        if (lane >= off) incl += v;
    }
    int wv = t >> 6;
    if (lane == 63) wsum[wv] = incl;
    __syncthreads();
    int woff = 0;
#pragma unroll
    for (int i = 0; i < 4; ++i) if (i < wv) woff += wsum[i];
    int excl = woff + incl - s;
    if (idx     < NN) rowptr[idx]     = excl;
    if (idx + 1 < NN) rowptr[idx + 1] = excl + d0;
    if (idx + 2 < NN) rowptr[idx + 2] = excl + d0 + d1;
    if (idx + 3 < NN) rowptr[idx + 3] = excl + d0 + d1 + d2;
    if (t == 255) part[blockIdx.x] = woff + incl;
}

__global__ void k_scan_add(int* __restrict__ rowptr, const int* __restrict__ part) {
    int i = blockIdx.x * blockDim.x + threadIdx.x;
    if (i < NN) rowptr[i] += part[i >> 10];
    if (i == 0) rowptr[NN] = NE;
}

__global__ void k_fill_rank(const int* __restrict__ src, const int* __restrict__ dst,
                            const int* __restrict__ rank, const int* __restrict__ rowptr,
                            int* __restrict__ csr_src, int ne) {
    int e = blockIdx.x * blockDim.x + threadIdx.x;
    if (e < ne) csr_src[rowptr[dst[e]] + rank[e]] = src[e];
}

__global__ __launch_bounds__(256) void k_pack(const int* __restrict__ rowptr,
                                              const int* __restrict__ csr,
                                              const float* __restrict__ dinv,
                                              int2* __restrict__ cc) {
    int n = blockIdx.x * 256 + threadIdx.x;
    if (n >= NN) return;
    float dn = dinv[n];
    for (int e = rowptr[n]; e < rowptr[n + 1]; ++e) {
        int s = csr[e];
        cc[e] = make_int2(s, __float_as_int(dinv[s] * dn));
    }
}

__global__ __launch_bounds__(256) void k_gemm_bf(const float* __restrict__ X,
                                                 const float* __restrict__ W,
                                                 unsigned short* __restrict__ Hb,
                                                 int nrows) {
    __shared__ float4 Ws4[64][16];
    __shared__ float  Xs[64][68];
    int tid = threadIdx.x;
    const float4* W4 = (const float4*)W;
    for (int i = tid; i < 64 * 16; i += 256) Ws4[i >> 4][i & 15] = W4[i];
    int row0 = blockIdx.x * 64;
    const float4* X4 = (const float4*)X;
    for (int i = tid; i < 64 * 16; i += 256) {
        int r = i >> 4, q = i & 15;
        int row = row0 + r;
        float4 v = make_float4(0.f, 0.f, 0.f, 0.f);
        if (row < nrows) v = X4[row * 16 + q];
        *((float4*)&Xs[r][q * 4]) = v;
    }
    __syncthreads();
    int c4 = tid & 15;
    int rg = tid >> 4;
    float4 acc0 = make_float4(0.f, 0.f, 0.f, 0.f);
    float4 acc1 = acc0, acc2 = acc0, acc3 = acc0;
#pragma unroll 4
    for (int k = 0; k < 64; ++k) {
        float4 w = Ws4[k][c4];
        float x0 = Xs[rg * 4 + 0][k];
        float x1 = Xs[rg * 4 + 1][k];
        float x2 = Xs[rg * 4 + 2][k];
        float x3 = Xs[rg * 4 + 3][k];
        acc0.x += x0 * w.x; acc0.y += x0 * w.y; acc0.z += x0 * w.z; acc0.w += x0 * w.w;
        acc1.x += x1 * w.x; acc1.y += x1 * w.y; acc1.z += x1 * w.z; acc1.w += x1 * w.w;
        acc2.x += x2 * w.x; acc2.y += x2 * w.y; acc2.z += x2 * w.z; acc2.w += x2 * w.w;
        acc3.x += x3 * w.x; acc3.y += x3 * w.y; acc3.z += x3 * w.z; acc3.w += x3 * w.w;
    }
    float4 accs[4] = {acc0, acc1, acc2, acc3};
#pragma unroll
    for (int i = 0; i < 4; ++i) {
        int row = row0 + rg * 4 + i;
        if (row < nrows) {
            ushort4 o;
            o.x = f2bf(accs[i].x); o.y = f2bf(accs[i].y);
            o.z = f2bf(accs[i].z); o.w = f2bf(accs[i].w);
            *((ushort4*)&Hb[row * 64 + c4 * 4]) = o;
        }
    }
}

// ---------------- shared gather core: 8 nodes/wave, 8-deep gather pipeline ----------------
// Depth 8: consume-distance = one full 8-edge iteration; 16 cache lines in
// flight per lane-group. Dummy slots (t>=deg) gather row 0 (L1-hot) with cf=0.
static __device__ __forceinline__ void gather8(const unsigned short* __restrict__ Hb,
                                               const int2* __restrict__ cc,
                                               int e0, int deg, int dmax, int cg,
                                               float acc[8]) {
#define LDE(T, S, C) { bool _v = (T) < deg; int2 _w = _v ? cc[e0 + (T)] : make_int2(0, 0); \
                       S = _w.x; C = __int_as_float(_w.y); }
#define GAT(U, S) U = *(const uint4*)(Hb + (size_t)(S) * 64 + cg * 8);
#define CONS(U, C) { acc[0] += bf_lo(U.x) * (C);  acc[1] += bf_hi(U.x) * (C); \
                     acc[2] += bf_lo(U.y) * (C);  acc[3] += bf_hi(U.y) * (C); \
                     acc[4] += bf_lo(U.z) * (C);  acc[5] += bf_hi(U.z) * (C); \
                     acc[6] += bf_lo(U.w) * (C);  acc[7] += bf_hi(U.w) * (C); }
    int s0, s1, s2, s3, s4, s5, s6, s7;
    float c0, c1, c2, c3, c4, c5, c6, c7;
    LDE(0, s0, c0); LDE(1, s1, c1); LDE(2, s2, c2); LDE(3, s3, c3);
    LDE(4, s4, c4); LDE(5, s5, c5); LDE(6, s6, c6); LDE(7, s7, c7);
    uint4 u0, u1, u2, u3, u4, u5, u6, u7;
    GAT(u0, s0); GAT(u1, s1); GAT(u2, s2); GAT(u3, s3);
    GAT(u4, s4); GAT(u5, s5); GAT(u6, s6); GAT(u7, s7);
    for (int t = 0; t < dmax; t += 8) {
        int sn0, sn1, sn2, sn3, sn4, sn5, sn6, sn7;
        float cn0, cn1, cn2, cn3, cn4, cn5, cn6, cn7;
        LDE(t +  8, sn0, cn0); LDE(t +  9, sn1, cn1);
        LDE(t + 10, sn2, cn2); LDE(t + 11, sn3, cn3);
        LDE(t + 12, sn4, cn4); LDE(t + 13, sn5, cn5);
        LDE(t + 14, sn6, cn6); LDE(t + 15, sn7, cn7);
        CONS(u0, c0); GAT(u0, sn0); c0 = cn0;
        CONS(u1, c1); GAT(u1, sn1); c1 = cn1;
        CONS(u2, c2); GAT(u2, sn2); c2 = cn2;
        CONS(u3, c3); GAT(u3, sn3); c3 = cn3;
        CONS(u4, c4); GAT(u4, sn4); c4 = cn4;
        CONS(u5, c5); GAT(u5, sn5); c5 = cn5;
        CONS(u6, c6); GAT(u6, sn6); c6 = cn6;
        CONS(u7, c7); GAT(u7, sn7); c7 = cn7;
    }
#undef LDE
#undef GAT
#undef CONS
}

// ---------------- reduce layer1 + gemm2 fused: h1 never touches HBM ----------------
__global__ __launch_bounds__(256) void k_reduce_g2(const unsigned short* __restrict__ Hb,
                                                   const int* __restrict__ rowptr,
                                                   const int* __restrict__ part,
                                                   const int2* __restrict__ cc,
                                                   const float* __restrict__ dinv,
                                                   const float* __restrict__ bias,
                                                   const float* __restrict__ W2,
                                                   unsigned short* __restrict__ Hb2) {
    __shared__ float4 Ws4[64][16];
    __shared__ float rows[32][68];
    int t = threadIdx.x;
    const float4* W4 = (const float4*)W2;
    for (int i = t; i < 1024; i += 256) Ws4[i >> 4][i & 15] = W4[i];   // hides under gather loop

    int n = blockIdx.x * 32 + (t >> 3);
    int cg = t & 7;
    bool nv = n < NN;
    float din = nv ? dinv[n] : 0.f;
    uint4 us = make_uint4(0u, 0u, 0u, 0u);
    int e0 = 0, deg = 0;
    if (nv) {
        us = *(const uint4*)(Hb + (size_t)n * 64 + cg * 8);
        int rp0 = rowptr[n] + part[n >> 10];
        int rp1 = rowptr[n + 1] + part[(n + 1) >> 10];
        e0 = rp0; deg = rp1 - rp0;
    }
    int dmax = deg;
    dmax = max(dmax, __shfl_xor(dmax, 8));
    dmax = max(dmax, __shfl_xor(dmax, 16));
    dmax = max(dmax, __shfl_xor(dmax, 32));

    float acc[8];
#pragma unroll
    for (int j = 0; j < 8; ++j) acc[j] = 0.f;
    gather8(Hb, cc, e0, deg, dmax, cg, acc);

    // h1 = relu(agg + self + b1) -> LDS rows
    float ddn = din * din;
    float4 b0 = *(const float4*)(bias + cg * 8);
    float4 b1 = *(const float4*)(bias + cg * 8 + 4);
    float4 o0, o1;
    o0.x = fmaxf(acc[0] + bf_lo(us.x) * ddn + b0.x, 0.f);
    o0.y = fmaxf(acc[1] + bf_hi(us.x) * ddn + b0.y, 0.f);
    o0.z = fmaxf(acc[2] + bf_lo(us.y) * ddn + b0.z, 0.f);
    o0.w = fmaxf(acc[3] + bf_hi(us.y) * ddn + b0.w, 0.f);
    o1.x = fmaxf(acc[4] + bf_lo(us.z) * ddn + b1.x, 0.f);
    o1.y = fmaxf(acc[5] + bf_hi(us.z) * ddn + b1.y, 0.f);
    o1.z = fmaxf(acc[6] + bf_lo(us.w) * ddn + b1.z, 0.f);
    o1.w = fmaxf(acc[7] + bf_hi(us.w) * ddn + b1.w, 0.f);
    int node = t >> 3;
    *(float4*)&rows[node][cg * 8]     = o0;
    *(float4*)&rows[node][cg * 8 + 4] = o1;
    __syncthreads();

    // gemm2: thread (node, c2) computes cols c2*8..c2*8+7 of Hb2[n]
    int c2 = t & 7;
    float a0 = 0.f, a1 = 0.f, a2 = 0.f, a3 = 0.f, a4 = 0.f, a5 = 0.f, a6 = 0.f, a7 = 0.f;
#pragma unroll 4
    for (int k = 0; k < 64; ++k) {
        float r = rows[node][k];
        float4 w0 = Ws4[k][c2 * 2];
        float4 w1 = Ws4[k][c2 * 2 + 1];
        a0 += r * w0.x; a1 += r * w0.y; a2 += r * w0.z; a3 += r * w0.w;
        a4 += r * w1.x; a5 += r * w1.y; a6 += r * w1.z; a7 += r * w1.w;
    }
    if (nv) {
        uint4 pk;
        pk.x = (unsigned int)f2bf(a0) | ((unsigned int)f2bf(a1) << 16);
        pk.y = (unsigned int)f2bf(a2) | ((unsigned int)f2bf(a3) << 16);
        pk.z = (unsigned int)f2bf(a4) | ((unsigned int)f2bf(a5) << 16);
        pk.w = (unsigned int)f2bf(a6) | ((unsigned int)f2bf(a7) << 16);
        *(uint4*)&Hb2[(size_t)n * 64 + c2 * 8] = pk;
    }
}

// ---------------- final reduce (layer 2): writes h to both output halves ----------------
__global__ __launch_bounds__(256) void k_reduce2(const unsigned short* __restrict__ Hb,
                                                 const int* __restrict__ rowptr,
                                                 const int* __restrict__ part,
                                                 const int2* __restrict__ cc,
                                                 const float* __restrict__ dinv,
                                                 const float* __restrict__ bias,
                                                 float* __restrict__ out0,
                                                 float* __restrict__ out1) {
    int n = blockIdx.x * 32 + (threadIdx.x >> 3);
    if (n >= NN) return;
    int cg = threadIdx.x & 7;
    float din = dinv[n];
    uint4 us = *(const uint4*)(Hb + (size_t)n * 64 + cg * 8);
    int rp0 = rowptr[n] + part[n >> 10];
    int rp1 = rowptr[n + 1] + part[(n + 1) >> 10];
    int e0 = rp0, deg = rp1 - rp0;
    int dmax = deg;
    dmax = max(dmax, __shfl_xor(dmax, 8));
    dmax = max(dmax, __shfl_xor(dmax, 16));
    dmax = max(dmax, __shfl_xor(dmax, 32));

    float acc[8];
#pragma unroll
    for (int j = 0; j < 8; ++j) acc[j] = 0.f;
    gather8(Hb, cc, e0, deg, dmax, cg, acc);

    float ddn = din * din;
    float4 b0 = *(const float4*)(bias + cg * 8);
    float4 b1 = *(const float4*)(bias + cg * 8 + 4);
    float4 o0, o1;
    o0.x = acc[0] + bf_lo(us.x) * ddn + b0.x;
    o0.y = acc[1] + bf_hi(us.x) * ddn + b0.y;
    o0.z = acc[2] + bf_lo(us.y) * ddn + b0.z;
    o0.w = acc[3] + bf_hi(us.y) * ddn + b0.w;
    o1.x = acc[4] + bf_lo(us.z) * ddn + b1.x;
    o1.y = acc[5] + bf_hi(us.z) * ddn + b1.y;
    o1.z = acc[6] + bf_lo(us.w) * ddn + b1.z;
    o1.w = acc[7] + bf_hi(us.w) * ddn + b1.w;
    *(float4*)(out0 + (size_t)n * 64 + cg * 8)     = o0;
    *(float4*)(out0 + (size_t)n * 64 + cg * 8 + 4) = o1;
    *(float4*)(out1 + (size_t)n * 64 + cg * 8)     = o0;
    *(float4*)(out1 + (size_t)n * 64 + cg * 8 + 4) = o1;
}

extern "C" void kernel_launch(void* const* d_in, const int* in_sizes, int n_in,
                              void* d_out, int out_size, void* d_ws, size_t ws_size,
                              hipStream_t stream) {
    const float* x  = (const float*)d_in[0];
    const int*   ei = (const int*)d_in[1];     // [2, NE]: src row then dst row
    const float* W1 = (const float*)d_in[2];
    const float* b1 = (const float*)d_in[3];
    const float* W2 = (const float*)d_in[4];
    const float* b2 = (const float*)d_in[5];
    const int* src = ei;
    const int* dst = ei + NE;

    float* A = (float*)d_out;                   // half 0: final h
    float* B = (float*)d_out + (size_t)NN * DD; // half 1: final h

    char* w = (char*)d_ws;
    size_t off = 0;
    auto alloc = [&](size_t bytes) { void* p = w + off; off += (bytes + 255) & ~(size_t)255; return p; };
    float* dinv   = (float*)alloc(NN * sizeof(float));
    int*   degi   = (int*)  alloc(NN * sizeof(int));            // legacy only
    int*   cnt    = (int*)  alloc(NN * sizeof(int));            // new: cseg aux (exactly KSEG*NW4 ints)
    int*   rowptr = (int*)  alloc((NN + 1) * sizeof(int));
    int*   part   = (int*)  alloc(512 * sizeof(int));
    int*   csr    = (int*)  alloc(NE * sizeof(int));            // legacy only
    int2*  cc     = (int2*) alloc(NE * sizeof(int2));           // {src, coef} packed, 9.6 MB
    void*  uni    = alloc((size_t)NN * DD * sizeof(unsigned short));
    unsigned char* Hh    = (unsigned char*)uni;
    unsigned char* rank8 = (unsigned char*)uni + (size_t)KCH3 * NN;
    unsigned short* Bb2  = (unsigned short*)uni;
    unsigned short* Bb1 = (unsigned short*)alloc((size_t)NN * DD * sizeof(unsigned short));
    int* rank = (int*)Bb1;                      // legacy rank aliases Bb1
    size_t off_total = off;

    bool new_path = (ws_size >= off_total);

    if (new_path) {
        // 1. hist (+rank capture) || gemm1 — independent, merged
        k_histgemm<<<HISTB + GEMMB, 1024, 0, stream>>>(dst, Hh, rank8, x, W1, Bb1);
        // 2-3. per-dst chunk prefix; seg3 fuses dinv + local rowptr + part
        dim3 cgrid((NW4 + 255) / 256, KSEG);
        k_cseg_sum<<<cgrid, 256, 0, stream>>>((unsigned int*)Hh, (unsigned int*)cnt);
        k_cseg_scan2<<<cgrid, 256, 0, stream>>>((unsigned int*)Hh, (const unsigned int*)cnt,
                                                rowptr, part, dinv);
        // 4. part scan (+rowptr[NN] park)
        k_scan_part<<<1, 128, 0, stream>>>(part, rowptr);
        // 5. fill + coef fused
        k_fill4<<<(NE / 4 + 255) / 256, 256, 0, stream>>>(src, dst, rank8, Hh, rowptr, part, dinv, cc);
        // 6. reduce layer1 + gemm2 fused -> Bb2 (H region now dead)
        k_reduce_g2<<<(NN + 31) / 32, 256, 0, stream>>>(Bb1, rowptr, part, cc, dinv, b1, W2, Bb2);
        // 7. final reduce -> both output halves
        k_reduce2<<<(NN + 31) / 32, 256, 0, stream>>>(Bb2, rowptr, part, cc, dinv, b2, A, B);
    } else {
        // legacy rank path
        hipMemsetAsync(degi, 0, NN * sizeof(int), stream);
        k_hist_rank<<<(NE + 255) / 256, 256, 0, stream>>>(dst, degi, rank, NE);
        k_scan_local<<<SNB, 256, 0, stream>>>(degi, rowptr, part, dinv);
        k_scan_part<<<1, 128, 0, stream>>>(part, rowptr);
        k_scan_add<<<(NN + 255) / 256, 256, 0, stream>>>(rowptr, part);
        hipMemsetAsync(part, 0, 512 * sizeof(int), stream);
        k_fill_rank<<<(NE + 255) / 256, 256, 0, stream>>>(src, dst, rank, rowptr, csr, NE);
        k_pack<<<(NN + 255) / 256, 256, 0, stream>>>(rowptr, csr, dinv, cc);
        k_gemm_bf<<<(NN + 63) / 64, 256, 0, stream>>>(x, W1, Bb1, NN);
        k_reduce_g2<<<(NN + 31) / 32, 256, 0, stream>>>(Bb1, rowptr, part, cc, dinv, b1, W2, Bb2);
        k_reduce2<<<(NN + 31) / 32, 256, 0, stream>>>(Bb2, rowptr, part, cc, dinv, b2, A, B);
    }
}

// Round 9
// 231.803 us; speedup vs baseline: 1.0600x; 1.0426x over previous
//
#include <hip/hip_runtime.h>

#define NN 100000
#define NE 1200000
#define DD 64
#define SCH 1024
#define SNB ((NN + SCH - 1) / SCH)              // 98 scan blocks

// ---- atomic-light CSR build: u8 LDS histogram + fused rank capture ----
#define KCH3 96                                 // edge chunks
#define CEH3 (NE / KCH3)                        // 12500 edges / chunk (exact)
#define P3 4                                    // dst partitions
#define BINS3 (NN / P3)                         // 25000 bins / partition
#define BINW3 (BINS3 / 4)                       // 6250 packed u32 words (25 KB LDS)
#define KSEG 4                                  // chunk-scan segments
#define KPS (KCH3 / KSEG)                       // 24 chunks per segment
#define NW4 (NN / 4)                            // 25000 packed u32 dst-words (NN = 4*NW4 exactly)
#define HISTB (KCH3 * P3)                       // 384 hist blocks
#define GEMMB ((NN + 255) / 256)                // 391 gemm blocks (256 rows each)

// bf16 helpers
static __device__ __forceinline__ unsigned short f2bf(float f) {
    unsigned int u = __float_as_uint(f);
    u += 0x7fffu + ((u >> 16) & 1u);
    return (unsigned short)(u >> 16);
}
static __device__ __forceinline__ float bf_lo(unsigned int u) { return __uint_as_float(u << 16); }
static __device__ __forceinline__ float bf_hi(unsigned int u) { return __uint_as_float(u & 0xffff0000u); }

// ---------------- merged: hist3 (blocks [0,HISTB)) || gemm1 (blocks [HISTB,..)) ----------------
__global__ __launch_bounds__(1024) void k_histgemm(const int* __restrict__ dst,
                                                   unsigned char* __restrict__ H,       // [KCH3][NN] u8
                                                   unsigned char* __restrict__ rank8,   // [NE] u8
                                                   const float* __restrict__ X,
                                                   const float* __restrict__ W,
                                                   unsigned short* __restrict__ Hb) {
    __shared__ union SM {
        unsigned int bins[BINW3];
        struct { float4 Ws4[64][16]; float Xs[64][68]; } g;
    } sm;
    int t = threadIdx.x;
    if (blockIdx.x < HISTB) {
        int k = blockIdx.x >> 2;          // P3 == 4
        int p = blockIdx.x & 3;
        for (int i = t; i < BINW3; i += 1024) sm.bins[i] = 0u;
        __syncthreads();
        int lo = p * BINS3;
        int beg = k * CEH3;
        for (int e4 = beg + t * 4; e4 < beg + CEH3; e4 += 4096) {
            int4 d4 = *(const int4*)&dst[e4];
            int dd[4] = {d4.x, d4.y, d4.z, d4.w};
#pragma unroll
            for (int j = 0; j < 4; ++j) {
                unsigned int r = (unsigned int)(dd[j] - lo);
                if (r < (unsigned int)BINS3) {
                    unsigned int sh = (r & 3u) << 3;
                    unsigned int old = atomicAdd(&sm.bins[r >> 2], 1u << sh);
                    rank8[e4 + j] = (unsigned char)((old >> sh) & 0xffu);
                }
            }
        }
        __syncthreads();
        unsigned int* Hw = (unsigned int*)(H + (size_t)k * NN + lo);
        for (int i = t; i < BINW3; i += 1024) Hw[i] = sm.bins[i];
    } else {
        const float4* W4 = (const float4*)W;
        sm.g.Ws4[t >> 4][t & 15] = W4[t];
        int row0 = (int)(blockIdx.x - HISTB) * 256;
        const float4* X4 = (const float4*)X;
        int r = t >> 4, q = t & 15;
#pragma unroll
        for (int s = 0; s < 4; ++s) {
            int row = row0 + s * 64 + r;
            float4 v = make_float4(0.f, 0.f, 0.f, 0.f);
            if (row < NN) v = X4[row * 16 + q];
            __syncthreads();
            *((float4*)&sm.g.Xs[r][q * 4]) = v;
            __syncthreads();
            float4 acc = make_float4(0.f, 0.f, 0.f, 0.f);
#pragma unroll 4
            for (int k = 0; k < 64; ++k) {
                float4 w = sm.g.Ws4[k][q];
                float x = sm.g.Xs[r][k];
                acc.x += x * w.x; acc.y += x * w.y; acc.z += x * w.z; acc.w += x * w.w;
            }
            if (row < NN) {
                ushort4 o;
                o.x = f2bf(acc.x); o.y = f2bf(acc.y); o.z = f2bf(acc.z); o.w = f2bf(acc.w);
                *((ushort4*)&Hb[(size_t)row * 64 + q * 4]) = o;
            }
        }
    }
}

// ---- segmented per-dst chunk prefix, pass A: per-segment sums ----
__global__ __launch_bounds__(256) void k_cseg_sum(const unsigned int* __restrict__ H32,
                                                  unsigned int* __restrict__ aux) {
    int wd = blockIdx.x * 256 + threadIdx.x;
    int seg = blockIdx.y;
    if (wd >= NW4) return;
    unsigned int s = 0;
#pragma unroll
    for (int k = 0; k < KPS; ++k)
        s += H32[(size_t)(seg * KPS + k) * NW4 + wd];
    aux[seg * NW4 + wd] = s;
}

// ---- pass B: prefix within segment; seg3 blocks ALSO fuse scan_local (dinv/rowptr/part) ----
__global__ __launch_bounds__(256) void k_cseg_scan2(unsigned int* __restrict__ H32,
                                                    const unsigned int* __restrict__ aux,
                                                    int* __restrict__ rowptr,   // LOCAL excl prefix
                                                    int* __restrict__ part,
                                                    float* __restrict__ dinv) {
    __shared__ int wsum[4];
    int t = threadIdx.x;
    int wd = blockIdx.x * 256 + t;
    int seg = blockIdx.y;
    bool valid = wd < NW4;
    unsigned int s = 0;
    if (valid) {
        unsigned int base = 0;
        for (int i = 0; i < seg; ++i) base += aux[i * NW4 + wd];
        s = base;
#pragma unroll
        for (int k = 0; k < KPS; ++k) {
            size_t idx = (size_t)(seg * KPS + k) * NW4 + wd;
            unsigned int v = H32[idx];
            H32[idx] = s;
            s += v;                      // byte-wise SWAR: no carry since deg < 256
        }
    }
    if (seg != KSEG - 1) return;         // uniform per block
    int d0 = valid ? (int)(s & 0xffu) : 0;
    int d1 = valid ? (int)((s >> 8) & 0xffu) : 0;
    int d2 = valid ? (int)((s >> 16) & 0xffu) : 0;
    int d3 = valid ? (int)(s >> 24) : 0;
    int idx = blockIdx.x * SCH + t * 4;  // == 4*wd
    if (valid) {
        float4 dv;
        dv.x = rsqrtf((float)d0 + 1.0f);
        dv.y = rsqrtf((float)d1 + 1.0f);
        dv.z = rsqrtf((float)d2 + 1.0f);
        dv.w = rsqrtf((float)d3 + 1.0f);
        *(float4*)&dinv[idx] = dv;
    }
    int ssum = d0 + d1 + d2 + d3;
    int lane = t & 63;
    int incl = ssum;
#pragma unroll
    for (int off = 1; off < 64; off <<= 1) {
        int v = __shfl_up(incl, off);
        if (lane >= off) incl += v;
    }
    int wv = t >> 6;
    if (lane == 63) wsum[wv] = incl;
    __syncthreads();
    int woff = 0;
#pragma unroll
    for (int i = 0; i < 4; ++i) if (i < wv) woff += wsum[i];
    int excl = woff + incl - ssum;
    if (valid) {
        int4 rp = make_int4(excl, excl + d0, excl + d0 + d1, excl + d0 + d1 + d2);
        *(int4*)&rowptr[idx] = rp;
    }
    if (t == 255) part[blockIdx.x] = woff + incl;
}

// ---- scan over the 98 block totals; also park last block's local total at rowptr[NN] ----
__global__ __launch_bounds__(128) void k_scan_part(int* __restrict__ part, int* __restrict__ rowptr) {
    __shared__ int sm[128];
    int t = threadIdx.x;
    int v = (t < SNB) ? part[t] : 0;
    sm[t] = v;
    __syncthreads();
    for (int off = 1; off < 128; off <<= 1) {
        int add = (t >= off) ? sm[t - off] : 0;
        __syncthreads();
        sm[t] += add;
        __syncthreads();
    }
    if (t == SNB - 1) rowptr[NN] = v;
    if (t < SNB) part[t] = sm[t] - v;
}

// ---- fill + coef fused: cc[pos] = {src, dinv[src]*dinv[dst]} ----
__global__ __launch_bounds__(256) void k_fill4(const int* __restrict__ src,
                                               const int* __restrict__ dst,
                                               const unsigned char* __restrict__ rank8,
                                               const unsigned char* __restrict__ H,
                                               const int* __restrict__ rowptr,
                                               const int* __restrict__ part,
                                               const float* __restrict__ dinv,
                                               int2* __restrict__ cc) {
    int e4 = (blockIdx.x * 256 + threadIdx.x) * 4;
    if (e4 >= NE) return;
    int4 d4 = *(const int4*)&dst[e4];
    int4 s4 = *(const int4*)&src[e4];
    unsigned int r4 = *(const unsigned int*)&rank8[e4];
    int dd[4] = {d4.x, d4.y, d4.z, d4.w};
    int ss[4] = {s4.x, s4.y, s4.z, s4.w};
    int k = e4 / CEH3;                   // CEH3 % 4 == 0 -> whole int4 in one chunk
#pragma unroll
    for (int j = 0; j < 4; ++j) {
        int d = dd[j], s = ss[j];
        int base = rowptr[d] + part[d >> 10] + (int)H[(size_t)k * NN + d];
        int pos = base + (int)((r4 >> (8 * j)) & 0xffu);
        cc[pos] = make_int2(s, __float_as_int(dinv[s] * dinv[d]));
    }
}

// ---------------- legacy fallback kernels ----------------
__global__ void k_hist_rank(const int* __restrict__ dst, int* __restrict__ degi,
                            int* __restrict__ rank, int ne) {
    int i = blockIdx.x * blockDim.x + threadIdx.x;
    if (i < ne) rank[i] = atomicAdd(&degi[dst[i]], 1);
}

__global__ __launch_bounds__(256) void k_scan_local(const int* __restrict__ degi,
                                                    int* __restrict__ rowptr,
                                                    int* __restrict__ part,
                                                    float* __restrict__ dinv) {
    __shared__ int wsum[4];
    int t = threadIdx.x;
    int idx = blockIdx.x * SCH + t * 4;
    int d0 = 0, d1 = 0, d2 = 0, d3 = 0;
    if (idx + 3 < NN) {
        int4 v = *(const int4*)&degi[idx];
        d0 = v.x; d1 = v.y; d2 = v.z; d3 = v.w;
        float4 dv;
        dv.x = rsqrtf((float)d0 + 1.0f);
        dv.y = rsqrtf((float)d1 + 1.0f);
        dv.z = rsqrtf((float)d2 + 1.0f);
        dv.w = rsqrtf((float)d3 + 1.0f);
        *(float4*)&dinv[idx] = dv;
    } else {
        if (idx     < NN) { d0 = degi[idx];     dinv[idx]     = rsqrtf((float)d0 + 1.0f); }
        if (idx + 1 < NN) { d1 = degi[idx + 1]; dinv[idx + 1] = rsqrtf((float)d1 + 1.0f); }
        if (idx + 2 < NN) { d2 = degi[idx + 2]; dinv[idx + 2] = rsqrtf((float)d2 + 1.0f); }
        if (idx + 3 < NN) { d3 = degi[idx + 3]; dinv[idx + 3] = rsqrtf((float)d3 + 1.0f); }
    }
    int s = d0 + d1 + d2 + d3;
    int lane = t & 63;
    int incl = s;
#pragma unroll
    for (int off = 1; off < 64; off <<= 1) {
        int v = __shfl_up(incl, off);
        if (lane >= off) incl += v;
    }
    int wv = t >> 6;
    if (lane == 63) wsum[wv] = incl;
    __syncthreads();
    int woff = 0;
#pragma unroll
    for (int i = 0; i < 4; ++i) if (i < wv) woff += wsum[i];
    int excl = woff + incl - s;
    if (idx     < NN) rowptr[idx]     = excl;
    if (idx + 1 < NN) rowptr[idx + 1] = excl + d0;
    if (idx + 2 < NN) rowptr[idx + 2] = excl + d0 + d1;
    if (idx + 3 < NN) rowptr[idx + 3] = excl + d0 + d1 + d2;
    if (t == 255) part[blockIdx.x] = woff + incl;
}

__global__ void k_scan_add(int* __restrict__ rowptr, const int* __restrict__ part) {
    int i = blockIdx.x * blockDim.x + threadIdx.x;
    if (i < NN) rowptr[i] += part[i >> 10];
    if (i == 0) rowptr[NN] = NE;
}

__global__ void k_fill_rank(const int* __restrict__ src, const int* __restrict__ dst,
                            const int* __restrict__ rank, const int* __restrict__ rowptr,
                            int* __restrict__ csr_src, int ne) {
    int e = blockIdx.x * blockDim.x + threadIdx.x;
    if (e < ne) csr_src[rowptr[dst[e]] + rank[e]] = src[e];
}

__global__ __launch_bounds__(256) void k_pack(const int* __restrict__ rowptr,
                                              const int* __restrict__ csr,
                                              const float* __restrict__ dinv,
                                              int2* __restrict__ cc) {
    int n = blockIdx.x * 256 + threadIdx.x;
    if (n >= NN) return;
    float dn = dinv[n];
    for (int e = rowptr[n]; e < rowptr[n + 1]; ++e) {
        int s = csr[e];
        cc[e] = make_int2(s, __float_as_int(dinv[s] * dn));
    }
}

__global__ __launch_bounds__(256) void k_gemm_bf(const float* __restrict__ X,
                                                 const float* __restrict__ W,
                                                 unsigned short* __restrict__ Hb,
                                                 int nrows) {
    __shared__ float4 Ws4[64][16];
    __shared__ float  Xs[64][68];
    int tid = threadIdx.x;
    const float4* W4 = (const float4*)W;
    for (int i = tid; i < 64 * 16; i += 256) Ws4[i >> 4][i & 15] = W4[i];
    int row0 = blockIdx.x * 64;
    const float4* X4 = (const float4*)X;
    for (int i = tid; i < 64 * 16; i += 256) {
        int r = i >> 4, q = i & 15;
        int row = row0 + r;
        float4 v = make_float4(0.f, 0.f, 0.f, 0.f);
        if (row < nrows) v = X4[row * 16 + q];
        *((float4*)&Xs[r][q * 4]) = v;
    }
    __syncthreads();
    int c4 = tid & 15;
    int rg = tid >> 4;
    float4 acc0 = make_float4(0.f, 0.f, 0.f, 0.f);
    float4 acc1 = acc0, acc2 = acc0, acc3 = acc0;
#pragma unroll 4
    for (int k = 0; k < 64; ++k) {
        float4 w = Ws4[k][c4];
        float x0 = Xs[rg * 4 + 0][k];
        float x1 = Xs[rg * 4 + 1][k];
        float x2 = Xs[rg * 4 + 2][k];
        float x3 = Xs[rg * 4 + 3][k];
        acc0.x += x0 * w.x; acc0.y += x0 * w.y; acc0.z += x0 * w.z; acc0.w += x0 * w.w;
        acc1.x += x1 * w.x; acc1.y += x1 * w.y; acc1.z += x1 * w.z; acc1.w += x1 * w.w;
        acc2.x += x2 * w.x; acc2.y += x2 * w.y; acc2.z += x2 * w.z; acc2.w += x2 * w.w;
        acc3.x += x3 * w.x; acc3.y += x3 * w.y; acc3.z += x3 * w.z; acc3.w += x3 * w.w;
    }
    float4 accs[4] = {acc0, acc1, acc2, acc3};
#pragma unroll
    for (int i = 0; i < 4; ++i) {
        int row = row0 + rg * 4 + i;
        if (row < nrows) {
            ushort4 o;
            o.x = f2bf(accs[i].x); o.y = f2bf(accs[i].y);
            o.z = f2bf(accs[i].z); o.w = f2bf(accs[i].w);
            *((ushort4*)&Hb[row * 64 + c4 * 4]) = o;
        }
    }
}

// ---------------- shared gather core: 8 nodes/wave, 4-deep pipeline, int2 stream ----------------
// Depth 4 is the measured optimum (r6=48us vs r8 depth-8=52us: +24 VGPR cost
// occupancy 47->34% with no latency-cover gain). Roofline note: each GAT
// instruction touches 16 cache lines (8 random 128B rows); the CU line-
// processing path (~1 line/cyc) puts the per-reduce floor at ~35-40us.
static __device__ __forceinline__ void gather8(const unsigned short* __restrict__ Hb,
                                               const int2* __restrict__ cc,
                                               int e0, int deg, int dmax, int cg,
                                               float acc[8]) {
#define LDE(T, S, C) { bool _v = (T) < deg; int2 _w = _v ? cc[e0 + (T)] : make_int2(0, 0); \
                       S = _w.x; C = __int_as_float(_w.y); }
#define GAT(U, S) U = *(const uint4*)(Hb + (size_t)(S) * 64 + cg * 8);
#define CONS(U, C) { acc[0] += bf_lo(U.x) * (C);  acc[1] += bf_hi(U.x) * (C); \
                     acc[2] += bf_lo(U.y) * (C);  acc[3] += bf_hi(U.y) * (C); \
                     acc[4] += bf_lo(U.z) * (C);  acc[5] += bf_hi(U.z) * (C); \
                     acc[6] += bf_lo(U.w) * (C);  acc[7] += bf_hi(U.w) * (C); }
    int s0, s1, s2, s3; float c0, c1, c2, c3;
    LDE(0, s0, c0); LDE(1, s1, c1); LDE(2, s2, c2); LDE(3, s3, c3);
    uint4 u0, u1, u2, u3;
    GAT(u0, s0); GAT(u1, s1); GAT(u2, s2); GAT(u3, s3);
    for (int t = 0; t < dmax; t += 4) {
        int sn0, sn1, sn2, sn3; float cn0, cn1, cn2, cn3;
        LDE(t + 4, sn0, cn0); LDE(t + 5, sn1, cn1);
        LDE(t + 6, sn2, cn2); LDE(t + 7, sn3, cn3);
        CONS(u0, c0); GAT(u0, sn0); c0 = cn0;
        CONS(u1, c1); GAT(u1, sn1); c1 = cn1;
        CONS(u2, c2); GAT(u2, sn2); c2 = cn2;
        CONS(u3, c3); GAT(u3, sn3); c3 = cn3;
    }
#undef LDE
#undef GAT
#undef CONS
}

// ---------------- reduce layer1 + gemm2 fused: h1 never touches HBM ----------------
__global__ __launch_bounds__(256) void k_reduce_g2(const unsigned short* __restrict__ Hb,
                                                   const int* __restrict__ rowptr,
                                                   const int* __restrict__ part,
                                                   const int2* __restrict__ cc,
                                                   const float* __restrict__ dinv,
                                                   const float* __restrict__ bias,
                                                   const float* __restrict__ W2,
                                                   unsigned short* __restrict__ Hb2) {
    __shared__ float4 Ws4[64][16];
    __shared__ float rows[32][68];
    int t = threadIdx.x;
    const float4* W4 = (const float4*)W2;
    for (int i = t; i < 1024; i += 256) Ws4[i >> 4][i & 15] = W4[i];   // hides under gather loop

    int n = blockIdx.x * 32 + (t >> 3);
    int cg = t & 7;
    bool nv = n < NN;
    float din = nv ? dinv[n] : 0.f;
    uint4 us = make_uint4(0u, 0u, 0u, 0u);
    int e0 = 0, deg = 0;
    if (nv) {
        us = *(const uint4*)(Hb + (size_t)n * 64 + cg * 8);
        int rp0 = rowptr[n] + part[n >> 10];
        int rp1 = rowptr[n + 1] + part[(n + 1) >> 10];
        e0 = rp0; deg = rp1 - rp0;
    }
    int dmax = deg;
    dmax = max(dmax, __shfl_xor(dmax, 8));
    dmax = max(dmax, __shfl_xor(dmax, 16));
    dmax = max(dmax, __shfl_xor(dmax, 32));

    float acc[8];
#pragma unroll
    for (int j = 0; j < 8; ++j) acc[j] = 0.f;
    gather8(Hb, cc, e0, deg, dmax, cg, acc);

    // h1 = relu(agg + self + b1) -> LDS rows
    float ddn = din * din;
    float4 b0 = *(const float4*)(bias + cg * 8);
    float4 b1 = *(const float4*)(bias + cg * 8 + 4);
    float4 o0, o1;
    o0.x = fmaxf(acc[0] + bf_lo(us.x) * ddn + b0.x, 0.f);
    o0.y = fmaxf(acc[1] + bf_hi(us.x) * ddn + b0.y, 0.f);
    o0.z = fmaxf(acc[2] + bf_lo(us.y) * ddn + b0.z, 0.f);
    o0.w = fmaxf(acc[3] + bf_hi(us.y) * ddn + b0.w, 0.f);
    o1.x = fmaxf(acc[4] + bf_lo(us.z) * ddn + b1.x, 0.f);
    o1.y = fmaxf(acc[5] + bf_hi(us.z) * ddn + b1.y, 0.f);
    o1.z = fmaxf(acc[6] + bf_lo(us.w) * ddn + b1.z, 0.f);
    o1.w = fmaxf(acc[7] + bf_hi(us.w) * ddn + b1.w, 0.f);
    int node = t >> 3;
    *(float4*)&rows[node][cg * 8]     = o0;
    *(float4*)&rows[node][cg * 8 + 4] = o1;
    __syncthreads();

    // gemm2: thread (node, c2) computes cols c2*8..c2*8+7 of Hb2[n]
    int c2 = t & 7;
    float a0 = 0.f, a1 = 0.f, a2 = 0.f, a3 = 0.f, a4 = 0.f, a5 = 0.f, a6 = 0.f, a7 = 0.f;
#pragma unroll 4
    for (int k = 0; k < 64; ++k) {
        float r = rows[node][k];
        float4 w0 = Ws4[k][c2 * 2];
        float4 w1 = Ws4[k][c2 * 2 + 1];
        a0 += r * w0.x; a1 += r * w0.y; a2 += r * w0.z; a3 += r * w0.w;
        a4 += r * w1.x; a5 += r * w1.y; a6 += r * w1.z; a7 += r * w1.w;
    }
    if (nv) {
        uint4 pk;
        pk.x = (unsigned int)f2bf(a0) | ((unsigned int)f2bf(a1) << 16);
        pk.y = (unsigned int)f2bf(a2) | ((unsigned int)f2bf(a3) << 16);
        pk.z = (unsigned int)f2bf(a4) | ((unsigned int)f2bf(a5) << 16);
        pk.w = (unsigned int)f2bf(a6) | ((unsigned int)f2bf(a7) << 16);
        *(uint4*)&Hb2[(size_t)n * 64 + c2 * 8] = pk;
    }
}

// ---------------- final reduce (layer 2): writes h to both output halves ----------------
__global__ __launch_bounds__(256) void k_reduce2(const unsigned short* __restrict__ Hb,
                                                 const int* __restrict__ rowptr,
                                                 const int* __restrict__ part,
                                                 const int2* __restrict__ cc,
                                                 const float* __restrict__ dinv,
                                                 const float* __restrict__ bias,
                                                 float* __restrict__ out0,
                                                 float* __restrict__ out1) {
    int n = blockIdx.x * 32 + (threadIdx.x >> 3);
    if (n >= NN) return;
    int cg = threadIdx.x & 7;
    float din = dinv[n];
    uint4 us = *(const uint4*)(Hb + (size_t)n * 64 + cg * 8);
    int rp0 = rowptr[n] + part[n >> 10];
    int rp1 = rowptr[n + 1] + part[(n + 1) >> 10];
    int e0 = rp0, deg = rp1 - rp0;
    int dmax = deg;
    dmax = max(dmax, __shfl_xor(dmax, 8));
    dmax = max(dmax, __shfl_xor(dmax, 16));
    dmax = max(dmax, __shfl_xor(dmax, 32));

    float acc[8];
#pragma unroll
    for (int j = 0; j < 8; ++j) acc[j] = 0.f;
    gather8(Hb, cc, e0, deg, dmax, cg, acc);

    float ddn = din * din;
    float4 b0 = *(const float4*)(bias + cg * 8);
    float4 b1 = *(const float4*)(bias + cg * 8 + 4);
    float4 o0, o1;
    o0.x = acc[0] + bf_lo(us.x) * ddn + b0.x;
    o0.y = acc[1] + bf_hi(us.x) * ddn + b0.y;
    o0.z = acc[2] + bf_lo(us.y) * ddn + b0.z;
    o0.w = acc[3] + bf_hi(us.y) * ddn + b0.w;
    o1.x = acc[4] + bf_lo(us.z) * ddn + b1.x;
    o1.y = acc[5] + bf_hi(us.z) * ddn + b1.y;
    o1.z = acc[6] + bf_lo(us.w) * ddn + b1.z;
    o1.w = acc[7] + bf_hi(us.w) * ddn + b1.w;
    *(float4*)(out0 + (size_t)n * 64 + cg * 8)     = o0;
    *(float4*)(out0 + (size_t)n * 64 + cg * 8 + 4) = o1;
    *(float4*)(out1 + (size_t)n * 64 + cg * 8)     = o0;
    *(float4*)(out1 + (size_t)n * 64 + cg * 8 + 4) = o1;
}

extern "C" void kernel_launch(void* const* d_in, const int* in_sizes, int n_in,
                              void* d_out, int out_size, void* d_ws, size_t ws_size,
                              hipStream_t stream) {
    const float* x  = (const float*)d_in[0];
    const int*   ei = (const int*)d_in[1];     // [2, NE]: src row then dst row
    const float* W1 = (const float*)d_in[2];
    const float* b1 = (const float*)d_in[3];
    const float* W2 = (const float*)d_in[4];
    const float* b2 = (const float*)d_in[5];
    const int* src = ei;
    const int* dst = ei + NE;

    float* A = (float*)d_out;                   // half 0: final h
    float* B = (float*)d_out + (size_t)NN * DD; // half 1: final h

    char* w = (char*)d_ws;
    size_t off = 0;
    auto alloc = [&](size_t bytes) { void* p = w + off; off += (bytes + 255) & ~(size_t)255; return p; };
    float* dinv   = (float*)alloc(NN * sizeof(float));
    int*   degi   = (int*)  alloc(NN * sizeof(int));            // legacy only
    int*   cnt    = (int*)  alloc(NN * sizeof(int));            // new: cseg aux (exactly KSEG*NW4 ints)
    int*   rowptr = (int*)  alloc((NN + 1) * sizeof(int));
    int*   part   = (int*)  alloc(512 * sizeof(int));
    int*   csr    = (int*)  alloc(NE * sizeof(int));            // legacy only
    int2*  cc     = (int2*) alloc(NE * sizeof(int2));           // {src, coef} packed, 9.6 MB
    void*  uni    = alloc((size_t)NN * DD * sizeof(unsigned short));
    unsigned char* Hh    = (unsigned char*)uni;
    unsigned char* rank8 = (unsigned char*)uni + (size_t)KCH3 * NN;
    unsigned short* Bb2  = (unsigned short*)uni;
    unsigned short* Bb1 = (unsigned short*)alloc((size_t)NN * DD * sizeof(unsigned short));
    int* rank = (int*)Bb1;                      // legacy rank aliases Bb1
    size_t off_total = off;

    bool new_path = (ws_size >= off_total);

    if (new_path) {
        // 1. hist (+rank capture) || gemm1 — independent, merged
        k_histgemm<<<HISTB + GEMMB, 1024, 0, stream>>>(dst, Hh, rank8, x, W1, Bb1);
        // 2-3. per-dst chunk prefix; seg3 fuses dinv + local rowptr + part
        dim3 cgrid((NW4 + 255) / 256, KSEG);
        k_cseg_sum<<<cgrid, 256, 0, stream>>>((unsigned int*)Hh, (unsigned int*)cnt);
        k_cseg_scan2<<<cgrid, 256, 0, stream>>>((unsigned int*)Hh, (const unsigned int*)cnt,
                                                rowptr, part, dinv);
        // 4. part scan (+rowptr[NN] park)
        k_scan_part<<<1, 128, 0, stream>>>(part, rowptr);
        // 5. fill + coef fused
        k_fill4<<<(NE / 4 + 255) / 256, 256, 0, stream>>>(src, dst, rank8, Hh, rowptr, part, dinv, cc);
        // 6. reduce layer1 + gemm2 fused -> Bb2 (H region now dead)
        k_reduce_g2<<<(NN + 31) / 32, 256, 0, stream>>>(Bb1, rowptr, part, cc, dinv, b1, W2, Bb2);
        // 7. final reduce -> both output halves
        k_reduce2<<<(NN + 31) / 32, 256, 0, stream>>>(Bb2, rowptr, part, cc, dinv, b2, A, B);
    } else {
        // legacy rank path
        hipMemsetAsync(degi, 0, NN * sizeof(int), stream);
        k_hist_rank<<<(NE + 255) / 256, 256, 0, stream>>>(dst, degi, rank, NE);
        k_scan_local<<<SNB, 256, 0, stream>>>(degi, rowptr, part, dinv);
        k_scan_part<<<1, 128, 0, stream>>>(part, rowptr);
        k_scan_add<<<(NN + 255) / 256, 256, 0, stream>>>(rowptr, part);
        hipMemsetAsync(part, 0, 512 * sizeof(int), stream);
        k_fill_rank<<<(NE + 255) / 256, 256, 0, stream>>>(src, dst, rank, rowptr, csr, NE);
        k_pack<<<(NN + 255) / 256, 256, 0, stream>>>(rowptr, csr, dinv, cc);
        k_gemm_bf<<<(NN + 63) / 64, 256, 0, stream>>>(x, W1, Bb1, NN);
        k_reduce_g2<<<(NN + 31) / 32, 256, 0, stream>>>(Bb1, rowptr, part, cc, dinv, b1, W2, Bb2);
        k_reduce2<<<(NN + 31) / 32, 256, 0, stream>>>(Bb2, rowptr, part, cc, dinv, b2, A, B);
    }
}

// Round 11
// 230.874 us; speedup vs baseline: 1.0642x; 1.0040x over previous
//
#include <hip/hip_runtime.h>

#define NN 100000
#define NE 1200000
#define DD 64
#define SCH 1024
#define SNB ((NN + SCH - 1) / SCH)              // 98 scan blocks

// ---- atomic-light CSR build: u8 LDS histogram + fused rank capture ----
#define KCH3 96                                 // edge chunks
#define CEH3 (NE / KCH3)                        // 12500 edges / chunk (exact)
#define P3 2                                    // dst partitions (halves dst re-read vs 4)
#define BINS3 (NN / P3)                         // 50000 bins / partition
#define BINW3 (BINS3 / 4)                       // 12500 packed u32 words (50 KB LDS)
#define NW4 (NN / 4)                            // 25000 packed u32 dst-words (NN = 4*NW4 exactly)
#define HISTB (KCH3 * P3)                       // 192 hist blocks
#define GEMMB ((NN + 255) / 256)                // 391 gemm blocks (256 rows each)

// bf16 helpers
static __device__ __forceinline__ unsigned short f2bf(float f) {
    unsigned int u = __float_as_uint(f);
    u += 0x7fffu + ((u >> 16) & 1u);
    return (unsigned short)(u >> 16);
}
static __device__ __forceinline__ float bf_lo(unsigned int u) { return __uint_as_float(u << 16); }
static __device__ __forceinline__ float bf_hi(unsigned int u) { return __uint_as_float(u & 0xffff0000u); }

// ---------------- merged: hist3 (blocks [0,HISTB)) || gemm1 (blocks [HISTB,..)) ----------------
__global__ __launch_bounds__(1024) void k_histgemm(const int* __restrict__ dst,
                                                   unsigned char* __restrict__ H,       // [KCH3][NN] u8
                                                   unsigned char* __restrict__ rank8,   // [NE] u8
                                                   const float* __restrict__ X,
                                                   const float* __restrict__ W,
                                                   unsigned short* __restrict__ Hb) {
    __shared__ union SM {
        unsigned int bins[BINW3];                              // 50 KB
        struct { float4 Ws4[64][16]; float Xs[64][68]; } g;    // 33.8 KB
    } sm;
    int t = threadIdx.x;
    if (blockIdx.x < HISTB) {
        int k = blockIdx.x >> 1;          // P3 == 2
        int p = blockIdx.x & 1;
        for (int i = t; i < BINW3; i += 1024) sm.bins[i] = 0u;
        __syncthreads();
        int lo = p * BINS3;
        int beg = k * CEH3;
        for (int e4 = beg + t * 4; e4 < beg + CEH3; e4 += 4096) {
            int4 d4 = *(const int4*)&dst[e4];
            int dd[4] = {d4.x, d4.y, d4.z, d4.w};
#pragma unroll
            for (int j = 0; j < 4; ++j) {
                unsigned int r = (unsigned int)(dd[j] - lo);
                if (r < (unsigned int)BINS3) {
                    unsigned int sh = (r & 3u) << 3;
                    unsigned int old = atomicAdd(&sm.bins[r >> 2], 1u << sh);
                    rank8[e4 + j] = (unsigned char)((old >> sh) & 0xffu);
                }
            }
        }
        __syncthreads();
        unsigned int* Hw = (unsigned int*)(H + (size_t)k * NN + lo);
        for (int i = t; i < BINW3; i += 1024) Hw[i] = sm.bins[i];
    } else {
        const float4* W4 = (const float4*)W;
        sm.g.Ws4[t >> 4][t & 15] = W4[t];
        int row0 = (int)(blockIdx.x - HISTB) * 256;
        const float4* X4 = (const float4*)X;
        int r = t >> 4, q = t & 15;
#pragma unroll
        for (int s = 0; s < 4; ++s) {
            int row = row0 + s * 64 + r;
            float4 v = make_float4(0.f, 0.f, 0.f, 0.f);
            if (row < NN) v = X4[row * 16 + q];
            __syncthreads();
            *((float4*)&sm.g.Xs[r][q * 4]) = v;
            __syncthreads();
            float4 acc = make_float4(0.f, 0.f, 0.f, 0.f);
#pragma unroll 4
            for (int k = 0; k < 64; ++k) {
                float4 w = sm.g.Ws4[k][q];
                float x = sm.g.Xs[r][k];
                acc.x += x * w.x; acc.y += x * w.y; acc.z += x * w.z; acc.w += x * w.w;
            }
            if (row < NN) {
                ushort4 o;
                o.x = f2bf(acc.x); o.y = f2bf(acc.y); o.z = f2bf(acc.z); o.w = f2bf(acc.w);
                *((ushort4*)&Hb[(size_t)row * 64 + q * 4]) = o;
            }
        }
    }
}

// ---- single-pass per-dst chunk prefix (SWAR over 4 packed u8 dsts) + fused scan_local ----
// One kernel replaces cseg_sum+cseg_scan2: reads/writes H once (19.2 MB vs 29.6),
// then computes dinv, local rowptr and part from the final packed totals.
__global__ __launch_bounds__(256) void k_cseg(unsigned int* __restrict__ H32,
                                              int* __restrict__ rowptr,   // LOCAL excl prefix
                                              int* __restrict__ part,
                                              float* __restrict__ dinv) {
    __shared__ int wsum[4];
    int t = threadIdx.x;
    int wd = blockIdx.x * 256 + t;
    bool valid = wd < NW4;
    unsigned int s = 0;
    if (valid) {
#pragma unroll 8
        for (int k = 0; k < KCH3; ++k) {
            size_t idx = (size_t)k * NW4 + wd;
            unsigned int v = H32[idx];
            H32[idx] = s;
            s += v;                      // byte-wise SWAR: no carry since deg < 256
        }
    }
    int d0 = valid ? (int)(s & 0xffu) : 0;
    int d1 = valid ? (int)((s >> 8) & 0xffu) : 0;
    int d2 = valid ? (int)((s >> 16) & 0xffu) : 0;
    int d3 = valid ? (int)(s >> 24) : 0;
    int idx = blockIdx.x * SCH + t * 4;  // == 4*wd
    if (valid) {
        float4 dv;
        dv.x = rsqrtf((float)d0 + 1.0f);
        dv.y = rsqrtf((float)d1 + 1.0f);
        dv.z = rsqrtf((float)d2 + 1.0f);
        dv.w = rsqrtf((float)d3 + 1.0f);
        *(float4*)&dinv[idx] = dv;
    }
    int ssum = d0 + d1 + d2 + d3;
    int lane = t & 63;
    int incl = ssum;
#pragma unroll
    for (int off = 1; off < 64; off <<= 1) {
        int v = __shfl_up(incl, off);
        if (lane >= off) incl += v;
    }
    int wv = t >> 6;
    if (lane == 63) wsum[wv] = incl;
    __syncthreads();
    int woff = 0;
#pragma unroll
    for (int i = 0; i < 4; ++i) if (i < wv) woff += wsum[i];
    int excl = woff + incl - ssum;
    if (valid) {
        int4 rp = make_int4(excl, excl + d0, excl + d0 + d1, excl + d0 + d1 + d2);
        *(int4*)&rowptr[idx] = rp;
    }
    if (t == 255) part[blockIdx.x] = woff + incl;
}

// ---- scan over the 98 block totals; also park last block's local total at rowptr[NN] ----
__global__ __launch_bounds__(128) void k_scan_part(int* __restrict__ part, int* __restrict__ rowptr) {
    __shared__ int sm[128];
    int t = threadIdx.x;
    int v = (t < SNB) ? part[t] : 0;
    sm[t] = v;
    __syncthreads();
    for (int off = 1; off < 128; off <<= 1) {
        int add = (t >= off) ? sm[t - off] : 0;
        __syncthreads();
        sm[t] += add;
        __syncthreads();
    }
    if (t == SNB - 1) rowptr[NN] = v;
    if (t < SNB) part[t] = sm[t] - v;
}

// ---- fill + coef fused: cc[pos] = {src, dinv[src]*dinv[dst]} ----
__global__ __launch_bounds__(256) void k_fill4(const int* __restrict__ src,
                                               const int* __restrict__ dst,
                                               const unsigned char* __restrict__ rank8,
                                               const unsigned char* __restrict__ H,
                                               const int* __restrict__ rowptr,
                                               const int* __restrict__ part,
                                               const float* __restrict__ dinv,
                                               int2* __restrict__ cc) {
    int e4 = (blockIdx.x * 256 + threadIdx.x) * 4;
    if (e4 >= NE) return;
    int4 d4 = *(const int4*)&dst[e4];
    int4 s4 = *(const int4*)&src[e4];
    unsigned int r4 = *(const unsigned int*)&rank8[e4];
    int dd[4] = {d4.x, d4.y, d4.z, d4.w};
    int ss[4] = {s4.x, s4.y, s4.z, s4.w};
    int k = e4 / CEH3;                   // CEH3 % 4 == 0 -> whole int4 in one chunk
#pragma unroll
    for (int j = 0; j < 4; ++j) {
        int d = dd[j], s = ss[j];
        int base = rowptr[d] + part[d >> 10] + (int)H[(size_t)k * NN + d];
        int pos = base + (int)((r4 >> (8 * j)) & 0xffu);
        cc[pos] = make_int2(s, __float_as_int(dinv[s] * dinv[d]));
    }
}

// ---------------- legacy fallback kernels ----------------
__global__ void k_hist_rank(const int* __restrict__ dst, int* __restrict__ degi,
                            int* __restrict__ rank, int ne) {
    int i = blockIdx.x * blockDim.x + threadIdx.x;
    if (i < ne) rank[i] = atomicAdd(&degi[dst[i]], 1);
}

__global__ __launch_bounds__(256) void k_scan_local(const int* __restrict__ degi,
                                                    int* __restrict__ rowptr,
                                                    int* __restrict__ part,
                                                    float* __restrict__ dinv) {
    __shared__ int wsum[4];
    int t = threadIdx.x;
    int idx = blockIdx.x * SCH + t * 4;
    int d0 = 0, d1 = 0, d2 = 0, d3 = 0;
    if (idx + 3 < NN) {
        int4 v = *(const int4*)&degi[idx];
        d0 = v.x; d1 = v.y; d2 = v.z; d3 = v.w;
        float4 dv;
        dv.x = rsqrtf((float)d0 + 1.0f);
        dv.y = rsqrtf((float)d1 + 1.0f);
        dv.z = rsqrtf((float)d2 + 1.0f);
        dv.w = rsqrtf((float)d3 + 1.0f);
        *(float4*)&dinv[idx] = dv;
    } else {
        if (idx     < NN) { d0 = degi[idx];     dinv[idx]     = rsqrtf((float)d0 + 1.0f); }
        if (idx + 1 < NN) { d1 = degi[idx + 1]; dinv[idx + 1] = rsqrtf((float)d1 + 1.0f); }
        if (idx + 2 < NN) { d2 = degi[idx + 2]; dinv[idx + 2] = rsqrtf((float)d2 + 1.0f); }
        if (idx + 3 < NN) { d3 = degi[idx + 3]; dinv[idx + 3] = rsqrtf((float)d3 + 1.0f); }
    }
    int s = d0 + d1 + d2 + d3;
    int lane = t & 63;
    int incl = s;
#pragma unroll
    for (int off = 1; off < 64; off <<= 1) {
        int v = __shfl_up(incl, off);
        if (lane >= off) incl += v;
    }
    int wv = t >> 6;
    if (lane == 63) wsum[wv] = incl;
    __syncthreads();
    int woff = 0;
#pragma unroll
    for (int i = 0; i < 4; ++i) if (i < wv) woff += wsum[i];
    int excl = woff + incl - s;
    if (idx     < NN) rowptr[idx]     = excl;
    if (idx + 1 < NN) rowptr[idx + 1] = excl + d0;
    if (idx + 2 < NN) rowptr[idx + 2] = excl + d0 + d1;
    if (idx + 3 < NN) rowptr[idx + 3] = excl + d0 + d1 + d2;
    if (t == 255) part[blockIdx.x] = woff + incl;
}

__global__ void k_scan_add(int* __restrict__ rowptr, const int* __restrict__ part) {
    int i = blockIdx.x * blockDim.x + threadIdx.x;
    if (i < NN) rowptr[i] += part[i >> 10];
    if (i == 0) rowptr[NN] = NE;
}

__global__ void k_fill_rank(const int* __restrict__ src, const int* __restrict__ dst,
                            const int* __restrict__ rank, const int* __restrict__ rowptr,
                            int* __restrict__ csr_src, int ne) {
    int e = blockIdx.x * blockDim.x + threadIdx.x;
    if (e < ne) csr_src[rowptr[dst[e]] + rank[e]] = src[e];
}

__global__ __launch_bounds__(256) void k_pack(const int* __restrict__ rowptr,
                                              const int* __restrict__ csr,
                                              const float* __restrict__ dinv,
                                              int2* __restrict__ cc) {
    int n = blockIdx.x * 256 + threadIdx.x;
    if (n >= NN) return;
    float dn = dinv[n];
    for (int e = rowptr[n]; e < rowptr[n + 1]; ++e) {
        int s = csr[e];
        cc[e] = make_int2(s, __float_as_int(dinv[s] * dn));
    }
}

__global__ __launch_bounds__(256) void k_gemm_bf(const float* __restrict__ X,
                                                 const float* __restrict__ W,
                                                 unsigned short* __restrict__ Hb,
                                                 int nrows) {
    __shared__ float4 Ws4[64][16];
    __shared__ float  Xs[64][68];
    int tid = threadIdx.x;
    const float4* W4 = (const float4*)W;
    for (int i = tid; i < 64 * 16; i += 256) Ws4[i >> 4][i & 15] = W4[i];
    int row0 = blockIdx.x * 64;
    const float4* X4 = (const float4*)X;
    for (int i = tid; i < 64 * 16; i += 256) {
        int r = i >> 4, q = i & 15;
        int row = row0 + r;
        float4 v = make_float4(0.f, 0.f, 0.f, 0.f);
        if (row < nrows) v = X4[row * 16 + q];
        *((float4*)&Xs[r][q * 4]) = v;
    }
    __syncthreads();
    int c4 = tid & 15;
    int rg = tid >> 4;
    float4 acc0 = make_float4(0.f, 0.f, 0.f, 0.f);
    float4 acc1 = acc0, acc2 = acc0, acc3 = acc0;
#pragma unroll 4
    for (int k = 0; k < 64; ++k) {
        float4 w = Ws4[k][c4];
        float x0 = Xs[rg * 4 + 0][k];
        float x1 = Xs[rg * 4 + 1][k];
        float x2 = Xs[rg * 4 + 2][k];
        float x3 = Xs[rg * 4 + 3][k];
        acc0.x += x0 * w.x; acc0.y += x0 * w.y; acc0.z += x0 * w.z; acc0.w += x0 * w.w;
        acc1.x += x1 * w.x; acc1.y += x1 * w.y; acc1.z += x1 * w.z; acc1.w += x1 * w.w;
        acc2.x += x2 * w.x; acc2.y += x2 * w.y; acc2.z += x2 * w.z; acc2.w += x2 * w.w;
        acc3.x += x3 * w.x; acc3.y += x3 * w.y; acc3.z += x3 * w.z; acc3.w += x3 * w.w;
    }
    float4 accs[4] = {acc0, acc1, acc2, acc3};
#pragma unroll
    for (int i = 0; i < 4; ++i) {
        int row = row0 + rg * 4 + i;
        if (row < nrows) {
            ushort4 o;
            o.x = f2bf(accs[i].x); o.y = f2bf(accs[i].y);
            o.z = f2bf(accs[i].z); o.w = f2bf(accs[i].w);
            *((ushort4*)&Hb[row * 64 + c4 * 4]) = o;
        }
    }
}

// ---------------- shared gather core: 8 nodes/wave, 4-deep pipeline, int2 stream ----------------
// Depth 4 is the measured optimum (r6/r9=48us vs r8 depth-8=52us: +24 VGPR cost
// occupancy 47->34% with no latency-cover gain; r7 degree-sort perm broke
// locality: FETCH +9MB, -12%). The reduces sit at a measured plateau where
// depth-2/4/8, iteration-balance, and coef-precompute all failed to move them.
static __device__ __forceinline__ void gather8(const unsigned short* __restrict__ Hb,
                                               const int2* __restrict__ cc,
                                               int e0, int deg, int dmax, int cg,
                                               float acc[8]) {
#define LDE(T, S, C) { bool _v = (T) < deg; int2 _w = _v ? cc[e0 + (T)] : make_int2(0, 0); \
                       S = _w.x; C = __int_as_float(_w.y); }
#define GAT(U, S) U = *(const uint4*)(Hb + (size_t)(S) * 64 + cg * 8);
#define CONS(U, C) { acc[0] += bf_lo(U.x) * (C);  acc[1] += bf_hi(U.x) * (C); \
                     acc[2] += bf_lo(U.y) * (C);  acc[3] += bf_hi(U.y) * (C); \
                     acc[4] += bf_lo(U.z) * (C);  acc[5] += bf_hi(U.z) * (C); \
                     acc[6] += bf_lo(U.w) * (C);  acc[7] += bf_hi(U.w) * (C); }
    int s0, s1, s2, s3; float c0, c1, c2, c3;
    LDE(0, s0, c0); LDE(1, s1, c1); LDE(2, s2, c2); LDE(3, s3, c3);
    uint4 u0, u1, u2, u3;
    GAT(u0, s0); GAT(u1, s1); GAT(u2, s2); GAT(u3, s3);
    for (int t = 0; t < dmax; t += 4) {
        int sn0, sn1, sn2, sn3; float cn0, cn1, cn2, cn3;
        LDE(t + 4, sn0, cn0); LDE(t + 5, sn1, cn1);
        LDE(t + 6, sn2, cn2); LDE(t + 7, sn3, cn3);
        CONS(u0, c0); GAT(u0, sn0); c0 = cn0;
        CONS(u1, c1); GAT(u1, sn1); c1 = cn1;
        CONS(u2, c2); GAT(u2, sn2); c2 = cn2;
        CONS(u3, c3); GAT(u3, sn3); c3 = cn3;
    }
#undef LDE
#undef GAT
#undef CONS
}

// ---------------- reduce layer1 + gemm2 fused: h1 never touches HBM ----------------
// Grid is exact: NN == 32 * 3125, so no bounds guard needed.
__global__ __launch_bounds__(256) void k_reduce_g2(const unsigned short* __restrict__ Hb,
                                                   const int* __restrict__ rowptr,
                                                   const int* __restrict__ part,
                                                   const int2* __restrict__ cc,
                                                   const float* __restrict__ dinv,
                                                   const float* __restrict__ bias,
                                                   const float* __restrict__ W2,
                                                   unsigned short* __restrict__ Hb2) {
    __shared__ float4 Ws4[64][16];
    __shared__ float rows[32][68];
    int t = threadIdx.x;
    const float4* W4 = (const float4*)W2;
    for (int i = t; i < 1024; i += 256) Ws4[i >> 4][i & 15] = W4[i];   // hides under gather loop

    int n = blockIdx.x * 32 + (t >> 3);
    int cg = t & 7;
    float din = dinv[n];
    uint4 us = *(const uint4*)(Hb + (size_t)n * 64 + cg * 8);
    int rp0 = rowptr[n] + part[n >> 10];
    int rp1 = rowptr[n + 1] + part[(n + 1) >> 10];
    int e0 = rp0, deg = rp1 - rp0;
    int dmax = deg;
    dmax = max(dmax, __shfl_xor(dmax, 8));
    dmax = max(dmax, __shfl_xor(dmax, 16));
    dmax = max(dmax, __shfl_xor(dmax, 32));

    float acc[8];
#pragma unroll
    for (int j = 0; j < 8; ++j) acc[j] = 0.f;
    gather8(Hb, cc, e0, deg, dmax, cg, acc);

    // h1 = relu(agg + self + b1) -> LDS rows
    float ddn = din * din;
    float4 b0 = *(const float4*)(bias + cg * 8);
    float4 b1 = *(const float4*)(bias + cg * 8 + 4);
    float4 o0, o1;
    o0.x = fmaxf(acc[0] + bf_lo(us.x) * ddn + b0.x, 0.f);
    o0.y = fmaxf(acc[1] + bf_hi(us.x) * ddn + b0.y, 0.f);
    o0.z = fmaxf(acc[2] + bf_lo(us.y) * ddn + b0.z, 0.f);
    o0.w = fmaxf(acc[3] + bf_hi(us.y) * ddn + b0.w, 0.f);
    o1.x = fmaxf(acc[4] + bf_lo(us.z) * ddn + b1.x, 0.f);
    o1.y = fmaxf(acc[5] + bf_hi(us.z) * ddn + b1.y, 0.f);
    o1.z = fmaxf(acc[6] + bf_lo(us.w) * ddn + b1.z, 0.f);
    o1.w = fmaxf(acc[7] + bf_hi(us.w) * ddn + b1.w, 0.f);
    int node = t >> 3;
    *(float4*)&rows[node][cg * 8]     = o0;
    *(float4*)&rows[node][cg * 8 + 4] = o1;
    __syncthreads();

    // gemm2: thread (node, c2) computes cols c2*8..c2*8+7 of Hb2[n]
    int c2 = t & 7;
    float a0 = 0.f, a1 = 0.f, a2 = 0.f, a3 = 0.f, a4 = 0.f, a5 = 0.f, a6 = 0.f, a7 = 0.f;
#pragma unroll 4
    for (int k = 0; k < 64; ++k) {
        float r = rows[node][k];
        float4 w0 = Ws4[k][c2 * 2];
        float4 w1 = Ws4[k][c2 * 2 + 1];
        a0 += r * w0.x; a1 += r * w0.y; a2 += r * w0.z; a3 += r * w0.w;
        a4 += r * w1.x; a5 += r * w1.y; a6 += r * w1.z; a7 += r * w1.w;
    }
    uint4 pk;
    pk.x = (unsigned int)f2bf(a0) | ((unsigned int)f2bf(a1) << 16);
    pk.y = (unsigned int)f2bf(a2) | ((unsigned int)f2bf(a3) << 16);
    pk.z = (unsigned int)f2bf(a4) | ((unsigned int)f2bf(a5) << 16);
    pk.w = (unsigned int)f2bf(a6) | ((unsigned int)f2bf(a7) << 16);
    *(uint4*)&Hb2[(size_t)n * 64 + c2 * 8] = pk;
}

// ---------------- final reduce (layer 2): writes h to both output halves ----------------
__global__ __launch_bounds__(256) void k_reduce2(const unsigned short* __restrict__ Hb,
                                                 const int* __restrict__ rowptr,
                                                 const int* __restrict__ part,
                                                 const int2* __restrict__ cc,
                                                 const float* __restrict__ dinv,
                                                 const float* __restrict__ bias,
                                                 float* __restrict__ out0,
                                                 float* __restrict__ out1) {
    int n = blockIdx.x * 32 + (threadIdx.x >> 3);
    int cg = threadIdx.x & 7;
    float din = dinv[n];
    uint4 us = *(const uint4*)(Hb + (size_t)n * 64 + cg * 8);
    int rp0 = rowptr[n] + part[n >> 10];
    int rp1 = rowptr[n + 1] + part[(n + 1) >> 10];
    int e0 = rp0, deg = rp1 - rp0;
    int dmax = deg;
    dmax = max(dmax, __shfl_xor(dmax, 8));
    dmax = max(dmax, __shfl_xor(dmax, 16));
    dmax = max(dmax, __shfl_xor(dmax, 32));

    float acc[8];
#pragma unroll
    for (int j = 0; j < 8; ++j) acc[j] = 0.f;
    gather8(Hb, cc, e0, deg, dmax, cg, acc);

    float ddn = din * din;
    float4 b0 = *(const float4*)(bias + cg * 8);
    float4 b1 = *(const float4*)(bias + cg * 8 + 4);
    float4 o0, o1;
    o0.x = acc[0] + bf_lo(us.x) * ddn + b0.x;
    o0.y = acc[1] + bf_hi(us.x) * ddn + b0.y;
    o0.z = acc[2] + bf_lo(us.y) * ddn + b0.z;
    o0.w = acc[3] + bf_hi(us.y) * ddn + b0.w;
    o1.x = acc[4] + bf_lo(us.z) * ddn + b1.x;
    o1.y = acc[5] + bf_hi(us.z) * ddn + b1.y;
    o1.z = acc[6] + bf_lo(us.w) * ddn + b1.z;
    o1.w = acc[7] + bf_hi(us.w) * ddn + b1.w;
    *(float4*)(out0 + (size_t)n * 64 + cg * 8)     = o0;
    *(float4*)(out0 + (size_t)n * 64 + cg * 8 + 4) = o1;
    *(float4*)(out1 + (size_t)n * 64 + cg * 8)     = o0;
    *(float4*)(out1 + (size_t)n * 64 + cg * 8 + 4) = o1;
}

extern "C" void kernel_launch(void* const* d_in, const int* in_sizes, int n_in,
                              void* d_out, int out_size, void* d_ws, size_t ws_size,
                              hipStream_t stream) {
    const float* x  = (const float*)d_in[0];
    const int*   ei = (const int*)d_in[1];     // [2, NE]: src row then dst row
    const float* W1 = (const float*)d_in[2];
    const float* b1 = (const float*)d_in[3];
    const float* W2 = (const float*)d_in[4];
    const float* b2 = (const float*)d_in[5];
    const int* src = ei;
    const int* dst = ei + NE;

    float* A = (float*)d_out;                   // half 0: final h
    float* B = (float*)d_out + (size_t)NN * DD; // half 1: final h

    char* w = (char*)d_ws;
    size_t off = 0;
    auto alloc = [&](size_t bytes) { void* p = w + off; off += (bytes + 255) & ~(size_t)255; return p; };
    float* dinv   = (float*)alloc(NN * sizeof(float));
    int*   degi   = (int*)  alloc(NN * sizeof(int));            // legacy only
    int*   cnt    = (int*)  alloc(NN * sizeof(int));            // legacy only
    int*   rowptr = (int*)  alloc((NN + 1) * sizeof(int));
    int*   part   = (int*)  alloc(512 * sizeof(int));
    int*   csr    = (int*)  alloc(NE * sizeof(int));            // legacy only
    int2*  cc     = (int2*) alloc(NE * sizeof(int2));           // {src, coef} packed, 9.6 MB
    void*  uni    = alloc((size_t)NN * DD * sizeof(unsigned short));
    unsigned char* Hh    = (unsigned char*)uni;
    unsigned char* rank8 = (unsigned char*)uni + (size_t)KCH3 * NN;
    unsigned short* Bb2  = (unsigned short*)uni;
    unsigned short* Bb1 = (unsigned short*)alloc((size_t)NN * DD * sizeof(unsigned short));
    int* rank = (int*)Bb1;                      // legacy rank aliases Bb1
    size_t off_total = off;

    bool new_path = (ws_size >= off_total);

    if (new_path) {
        // 1. hist (+rank capture) || gemm1 — independent, merged
        k_histgemm<<<HISTB + GEMMB, 1024, 0, stream>>>(dst, Hh, rank8, x, W1, Bb1);
        // 2. single-pass per-dst chunk prefix + dinv + local rowptr + part
        k_cseg<<<(NW4 + 255) / 256, 256, 0, stream>>>((unsigned int*)Hh, rowptr, part, dinv);
        // 3. part scan (+rowptr[NN] park)
        k_scan_part<<<1, 128, 0, stream>>>(part, rowptr);
        // 4. fill + coef fused
        k_fill4<<<(NE / 4 + 255) / 256, 256, 0, stream>>>(src, dst, rank8, Hh, rowptr, part, dinv, cc);
        // 5. reduce layer1 + gemm2 fused -> Bb2 (H region now dead)
        k_reduce_g2<<<NN / 32, 256, 0, stream>>>(Bb1, rowptr, part, cc, dinv, b1, W2, Bb2);
        // 6. final reduce -> both output halves
        k_reduce2<<<NN / 32, 256, 0, stream>>>(Bb2, rowptr, part, cc, dinv, b2, A, B);
    } else {
        // legacy rank path
        hipMemsetAsync(degi, 0, NN * sizeof(int), stream);
        k_hist_rank<<<(NE + 255) / 256, 256, 0, stream>>>(dst, degi, rank, NE);
        k_scan_local<<<SNB, 256, 0, stream>>>(degi, rowptr, part, dinv);
        k_scan_part<<<1, 128, 0, stream>>>(part, rowptr);
        k_scan_add<<<(NN + 255) / 256, 256, 0, stream>>>(rowptr, part);
        hipMemsetAsync(part, 0, 512 * sizeof(int), stream);
        k_fill_rank<<<(NE + 255) / 256, 256, 0, stream>>>(src, dst, rank, rowptr, csr, NE);
        k_pack<<<(NN + 255) / 256, 256, 0, stream>>>(rowptr, csr, dinv, cc);
        k_gemm_bf<<<(NN + 63) / 64, 256, 0, stream>>>(x, W1, Bb1, NN);
        k_reduce_g2<<<NN / 32, 256, 0, stream>>>(Bb1, rowptr, part, cc, dinv, b1, W2, Bb2);
        k_reduce2<<<NN / 32, 256, 0, stream>>>(Bb2, rowptr, part, cc, dinv, b2, A, B);
    }
}